// Round 1
// baseline (191.087 us; speedup 1.0000x reference)
//
#include <hip/hip_runtime.h>
#include <hip/hip_bf16.h>
#include <stdint.h>

#define B_ 4
#define T_ 2048
#define D_ 512
#define H_ 8
#define DH_ 64
#define M_TOT (B_*T_)     // 8192
#define N_QKV (3*D_)      // 1536
#define SCALE_ 0.125f

typedef __attribute__((ext_vector_type(8))) short short8;
typedef __attribute__((ext_vector_type(8))) unsigned short ushort8;
typedef __attribute__((ext_vector_type(4))) float f32x4;

static __device__ __forceinline__ unsigned short f2bf(float f) {
    union { float f; unsigned u; } v; v.f = f;
    unsigned r = v.u + 0x7fffu + ((v.u >> 16) & 1u);
    return (unsigned short)(r >> 16);
}

// ---------------------------------------------------------------------------
// prep: x -> bf16 (vectorized); w_qkv, w_out -> bf16 transposed [N][K]
// ---------------------------------------------------------------------------
__global__ __launch_bounds__(256) void prep_kernel(
    const float* __restrict__ x, const float* __restrict__ w_qkv,
    const float* __restrict__ w_out,
    unsigned short* __restrict__ x_bf, unsigned short* __restrict__ wqkvT,
    unsigned short* __restrict__ woutT)
{
    const int NX  = M_TOT * D_ / 8;   // 524288 threads, 8 elems each
    const int NW1 = D_ * N_QKV;       // 786432
    const int NW2 = D_ * D_;          // 262144
    int tid = blockIdx.x * 256 + threadIdx.x;
    if (tid < NX) {
        int i = tid * 8;
        f32x4 a = *(const f32x4*)(x + i);
        f32x4 b = *(const f32x4*)(x + i + 4);
        ushort8 o;
        o[0] = f2bf(a[0]); o[1] = f2bf(a[1]); o[2] = f2bf(a[2]); o[3] = f2bf(a[3]);
        o[4] = f2bf(b[0]); o[5] = f2bf(b[1]); o[6] = f2bf(b[2]); o[7] = f2bf(b[3]);
        *(ushort8*)(x_bf + i) = o;
    } else if (tid < NX + NW1) {
        int idx = tid - NX;
        int k = idx & 511, n = idx >> 9;
        wqkvT[n * 512 + k] = f2bf(w_qkv[k * N_QKV + n]);
    } else if (tid < NX + NW1 + NW2) {
        int idx = tid - NX - NW1;
        int k = idx & 511, n = idx >> 9;
        woutT[n * 512 + k] = f2bf(w_out[k * D_ + n]);
    }
}

// ---------------------------------------------------------------------------
// GEMM body: C[128][128] tile, A[M][K] bf16 row-major, Bt[N][K] bf16 row-major
// 256 thr = 4 waves (2x2), each wave 64x64 = 4x4 frags of 16x16x32 MFMA.
// LDS padded to 40 elems/row (80B stride -> conflict-free-ish frag reads).
// ---------------------------------------------------------------------------
#define LDSPAD 40

__device__ __forceinline__ void gemm_tile_128(
    const unsigned short* __restrict__ A, const unsigned short* __restrict__ Bt,
    int K, int bm, int bn,
    unsigned short* sA, unsigned short* sB, f32x4 acc[4][4])
{
    const int tid = threadIdx.x;
    const int w = tid >> 6, l = tid & 63;
    const int wr = (w >> 1) * 64, wc = (w & 1) * 64;
#pragma unroll
    for (int mi = 0; mi < 4; ++mi)
#pragma unroll
        for (int ni = 0; ni < 4; ++ni)
#pragma unroll
            for (int r = 0; r < 4; ++r) acc[mi][ni][r] = 0.f;

    for (int kt = 0; kt < K; kt += 32) {
#pragma unroll
        for (int c = 0; c < 2; ++c) {
            int chunk = tid + c * 256;      // 0..511
            int row = chunk >> 2;           // 0..127
            int col8 = (chunk & 3) * 8;     // 0,8,16,24
            *(ushort8*)(sA + row * LDSPAD + col8) =
                *(const ushort8*)(A + (size_t)(bm + row) * K + kt + col8);
            *(ushort8*)(sB + row * LDSPAD + col8) =
                *(const ushort8*)(Bt + (size_t)(bn + row) * K + kt + col8);
        }
        __syncthreads();
        short8 af[4], bfr[4];
#pragma unroll
        for (int i = 0; i < 4; ++i) {
            af[i]  = *(const short8*)(sA + (wr + i * 16 + (l & 15)) * LDSPAD + (l >> 4) * 8);
            bfr[i] = *(const short8*)(sB + (wc + i * 16 + (l & 15)) * LDSPAD + (l >> 4) * 8);
        }
#pragma unroll
        for (int mi = 0; mi < 4; ++mi)
#pragma unroll
            for (int ni = 0; ni < 4; ++ni)
                acc[mi][ni] = __builtin_amdgcn_mfma_f32_16x16x32_bf16(
                    af[mi], bfr[ni], acc[mi][ni], 0, 0, 0);
        __syncthreads();
    }
}

__global__ __launch_bounds__(256) void gemm_qkv_kernel(
    const unsigned short* __restrict__ A, const unsigned short* __restrict__ Bt,
    unsigned short* __restrict__ qkv)
{
    __shared__ __align__(16) unsigned short sA[128 * LDSPAD];
    __shared__ __align__(16) unsigned short sB[128 * LDSPAD];
    f32x4 acc[4][4];
    int bn = blockIdx.x * 128, bm = blockIdx.y * 128;
    gemm_tile_128(A, Bt, 512, bm, bn, sA, sB, acc);
    const int l = threadIdx.x & 63, w = threadIdx.x >> 6;
    const int wr = (w >> 1) * 64, wc = (w & 1) * 64;
#pragma unroll
    for (int mi = 0; mi < 4; ++mi)
#pragma unroll
        for (int ni = 0; ni < 4; ++ni)
#pragma unroll
            for (int r = 0; r < 4; ++r) {
                int row = bm + wr + mi * 16 + (l >> 4) * 4 + r;
                int col = bn + wc + ni * 16 + (l & 15);
                float v = acc[mi][ni][r];
                if (col < D_) v *= SCALE_;           // fold softmax scale into Q
                qkv[(size_t)row * N_QKV + col] = f2bf(v);
            }
}

__global__ __launch_bounds__(256) void gemm_out_kernel(
    const unsigned short* __restrict__ A, const unsigned short* __restrict__ Bt,
    const float* __restrict__ b_out, const float* __restrict__ m,
    float* __restrict__ out)
{
    __shared__ __align__(16) unsigned short sA[128 * LDSPAD];
    __shared__ __align__(16) unsigned short sB[128 * LDSPAD];
    f32x4 acc[4][4];
    int bn = blockIdx.x * 128, bm = blockIdx.y * 128;
    gemm_tile_128(A, Bt, 512, bm, bn, sA, sB, acc);
    const int l = threadIdx.x & 63, w = threadIdx.x >> 6;
    const int wr = (w >> 1) * 64, wc = (w & 1) * 64;
#pragma unroll
    for (int mi = 0; mi < 4; ++mi)
#pragma unroll
        for (int ni = 0; ni < 4; ++ni)
#pragma unroll
            for (int r = 0; r < 4; ++r) {
                int row = bm + wr + mi * 16 + (l >> 4) * 4 + r;
                int col = bn + wc + ni * 16 + (l & 15);
                out[(size_t)row * D_ + col] = (acc[mi][ni][r] + b_out[col]) * m[row];
            }
}

// ---------------------------------------------------------------------------
// Flash attention: one block = one (b,h) x 64 Q-rows. 4 waves x 16 rows.
// KV tiles of 64, causal tile skip. Online softmax, 16-lane group reduce.
// ---------------------------------------------------------------------------
__global__ __launch_bounds__(256) void attn_kernel(
    const unsigned short* __restrict__ qkv, const float* __restrict__ m,
    unsigned short* __restrict__ o_bf)
{
    __shared__ __align__(16) unsigned short sK[64 * 72];   // [j][dh] pad 72
    __shared__ __align__(16) unsigned short sV[64 * 72];   // [dh][j] pad 72 (transposed)
    __shared__ __align__(16) unsigned short sP[4][16 * 72];
    __shared__ float sMj[64];

    const int tid = threadIdx.x, w = tid >> 6, l = tid & 63;
    const int bh = blockIdx.y, bb = bh >> 3, h = bh & 7;
    const int qb = blockIdx.x * 64;

    // Q fragments (already scaled by 1/8 in gemm_qkv epilogue)
    const int qrow = qb + w * 16 + (l & 15);
    short8 aq[2];
#pragma unroll
    for (int kk = 0; kk < 2; ++kk)
        aq[kk] = *(const short8*)(qkv + (size_t)(bb * T_ + qrow) * N_QKV
                                  + h * 64 + kk * 32 + (l >> 4) * 8);

    f32x4 oacc[4];
    float mrun[4], lrun[4];
#pragma unroll
    for (int r = 0; r < 4; ++r) {
        mrun[r] = -1e30f; lrun[r] = 0.f;
        oacc[r][0] = 0.f; oacc[r][1] = 0.f; oacc[r][2] = 0.f; oacc[r][3] = 0.f;
    }

    const int jt_max = blockIdx.x;     // causal: only tiles with j0 <= qb+63
    for (int jt = 0; jt <= jt_max; ++jt) {
        const int j0 = jt * 64;
        {   // stage K row-major, V transposed, m values
            int row = tid >> 2;
            int c16 = (tid & 3) * 16;
            const unsigned short* kg = qkv + (size_t)(bb * T_ + j0 + row) * N_QKV + 512 + h * 64 + c16;
            ushort8 k0 = *(const ushort8*)kg;
            ushort8 k1 = *(const ushort8*)(kg + 8);
            *(ushort8*)(sK + row * 72 + c16)     = k0;
            *(ushort8*)(sK + row * 72 + c16 + 8) = k1;
            const unsigned short* vg = qkv + (size_t)(bb * T_ + j0 + row) * N_QKV + 1024 + h * 64 + c16;
            ushort8 v0 = *(const ushort8*)vg;
            ushort8 v1 = *(const ushort8*)(vg + 8);
#pragma unroll
            for (int e = 0; e < 8; ++e) sV[(c16 + e) * 72 + row] = v0[e];
#pragma unroll
            for (int e = 0; e < 8; ++e) sV[(c16 + 8 + e) * 72 + row] = v1[e];
            if (tid < 64) sMj[tid] = m[bb * T_ + j0 + tid];
        }
        __syncthreads();

        // S = Q K^T  (16 rows x 64 keys per wave)
        f32x4 s[4];
#pragma unroll
        for (int f = 0; f < 4; ++f) {
            f32x4 sacc = {0.f, 0.f, 0.f, 0.f};
#pragma unroll
            for (int kk = 0; kk < 2; ++kk) {
                short8 bk = *(const short8*)(sK + (f * 16 + (l & 15)) * 72 + kk * 32 + (l >> 4) * 8);
                sacc = __builtin_amdgcn_mfma_f32_16x16x32_bf16(aq[kk], bk, sacc, 0, 0, 0);
            }
            s[f] = sacc;
        }
        // mask: causal + key padding
        const int ib = qb + w * 16 + (l >> 4) * 4;
#pragma unroll
        for (int f = 0; f < 4; ++f) {
            int jg = j0 + f * 16 + (l & 15);
            bool jvalid = (sMj[f * 16 + (l & 15)] != 0.f);
#pragma unroll
            for (int r = 0; r < 4; ++r)
                if (jg > ib + r || !jvalid) s[f][r] = -1e30f;
        }
        // online softmax (16-lane group holds one row's 64 keys across 4 frags)
        float mnew[4], scl[4], ls[4];
#pragma unroll
        for (int r = 0; r < 4; ++r) {
            float v = fmaxf(fmaxf(s[0][r], s[1][r]), fmaxf(s[2][r], s[3][r]));
#pragma unroll
            for (int off = 1; off < 16; off <<= 1) v = fmaxf(v, __shfl_xor(v, off, 64));
            mnew[r] = fmaxf(mrun[r], v);
            scl[r] = __expf(mrun[r] - mnew[r]);
            mrun[r] = mnew[r];
            ls[r] = 0.f;
        }
#pragma unroll
        for (int f = 0; f < 4; ++f)
#pragma unroll
            for (int r = 0; r < 4; ++r) {
                float p = __expf(s[f][r] - mnew[r]);
                s[f][r] = p;
                ls[r] += p;
            }
#pragma unroll
        for (int r = 0; r < 4; ++r) {
            float v = ls[r];
#pragma unroll
            for (int off = 1; off < 16; off <<= 1) v += __shfl_xor(v, off, 64);
            lrun[r] = lrun[r] * scl[r] + v;
        }
#pragma unroll
        for (int fd = 0; fd < 4; ++fd)
#pragma unroll
            for (int r = 0; r < 4; ++r) oacc[fd][r] *= scl[r];

        // P -> LDS (bf16), then PV MFMA. Per-wave region; wave-internal RAW
        // ordered by the explicit lgkmcnt(0).
#pragma unroll
        for (int f = 0; f < 4; ++f)
#pragma unroll
            for (int r = 0; r < 4; ++r)
                sP[w][((l >> 4) * 4 + r) * 72 + f * 16 + (l & 15)] = f2bf(s[f][r]);
        asm volatile("s_waitcnt lgkmcnt(0)" ::: "memory");

        short8 pa[2];
#pragma unroll
        for (int kk = 0; kk < 2; ++kk)
            pa[kk] = *(const short8*)(sP[w] + (l & 15) * 72 + kk * 32 + (l >> 4) * 8);
#pragma unroll
        for (int fd = 0; fd < 4; ++fd)
#pragma unroll
            for (int kk = 0; kk < 2; ++kk) {
                short8 bv = *(const short8*)(sV + (fd * 16 + (l & 15)) * 72 + kk * 32 + (l >> 4) * 8);
                oacc[fd] = __builtin_amdgcn_mfma_f32_16x16x32_bf16(pa[kk], bv, oacc[fd], 0, 0, 0);
            }
        __syncthreads();
    }

    // epilogue: O / l, write bf16 [8192][512]
#pragma unroll
    for (int fd = 0; fd < 4; ++fd)
#pragma unroll
        for (int r = 0; r < 4; ++r) {
            int rg = qb + w * 16 + (l >> 4) * 4 + r;
            float v = (lrun[r] > 0.f) ? oacc[fd][r] / lrun[r] : 0.f;
            o_bf[(size_t)(bb * T_ + rg) * D_ + h * 64 + fd * 16 + (l & 15)] = f2bf(v);
        }
}

// ---------------------------------------------------------------------------
extern "C" void kernel_launch(void* const* d_in, const int* in_sizes, int n_in,
                              void* d_out, int out_size, void* d_ws, size_t ws_size,
                              hipStream_t stream)
{
    const float* x     = (const float*)d_in[0];
    const float* m     = (const float*)d_in[1];
    const float* w_qkv = (const float*)d_in[2];
    const float* w_out = (const float*)d_in[3];
    const float* b_out = (const float*)d_in[4];
    float* out = (float*)d_out;

    char* ws = (char*)d_ws;
    unsigned short* x_bf   = (unsigned short*)(ws);                 //  8 MB [8192][512]
    unsigned short* wqkvT  = (unsigned short*)(ws + 8388608);       //  1.5 MB [1536][512]
    unsigned short* woutT  = (unsigned short*)(ws + 9961472);       //  0.5 MB [512][512]
    unsigned short* qkv_bf = (unsigned short*)(ws + 10485760);      // 24 MB [8192][1536]
    unsigned short* o_bf   = (unsigned short*)(ws + 35651584);      //  8 MB [8192][512]
    // total 44 MB of d_ws

    hipLaunchKernelGGL(prep_kernel, dim3(6144), dim3(256), 0, stream,
                       x, w_qkv, w_out, x_bf, wqkvT, woutT);
    hipLaunchKernelGGL(gemm_qkv_kernel, dim3(12, 64), dim3(256), 0, stream,
                       x_bf, wqkvT, qkv_bf);
    hipLaunchKernelGGL(attn_kernel, dim3(32, 32), dim3(256), 0, stream,
                       qkv_bf, m, o_bf);
    hipLaunchKernelGGL(gemm_out_kernel, dim3(4, 64), dim3(256), 0, stream,
                       o_bf, woutT, b_out, m, out);
}

// Round 2
// 154.436 us; speedup vs baseline: 1.2373x; 1.2373x over previous
//
#include <hip/hip_runtime.h>
#include <hip/hip_bf16.h>
#include <stdint.h>

#define B_ 4
#define T_ 2048
#define D_ 512
#define H_ 8
#define DH_ 64
#define M_TOT (B_*T_)     // 8192
#define N_QKV (3*D_)      // 1536
// 0.125 * log2(e): folds both softmax scale and exp->exp2 conversion into Q
#define QSCALE_ 0.18033688011112043f

typedef __attribute__((ext_vector_type(8))) short short8;
typedef __attribute__((ext_vector_type(8))) unsigned short ushort8;
typedef __attribute__((ext_vector_type(4))) float f32x4;

static __device__ __forceinline__ unsigned short f2bf(float f) {
    union { float f; unsigned u; } v; v.f = f;
    unsigned r = v.u + 0x7fffu + ((v.u >> 16) & 1u);
    return (unsigned short)(r >> 16);
}

// ---------------------------------------------------------------------------
// prep: x -> bf16 (vectorized); w_qkv, w_out -> bf16 transposed [N][K]
// ---------------------------------------------------------------------------
__global__ __launch_bounds__(256) void prep_kernel(
    const float* __restrict__ x, const float* __restrict__ w_qkv,
    const float* __restrict__ w_out,
    unsigned short* __restrict__ x_bf, unsigned short* __restrict__ wqkvT,
    unsigned short* __restrict__ woutT)
{
    const int NX  = M_TOT * D_ / 8;
    const int NW1 = D_ * N_QKV;
    const int NW2 = D_ * D_;
    int tid = blockIdx.x * 256 + threadIdx.x;
    if (tid < NX) {
        int i = tid * 8;
        f32x4 a = *(const f32x4*)(x + i);
        f32x4 b = *(const f32x4*)(x + i + 4);
        ushort8 o;
        o[0] = f2bf(a[0]); o[1] = f2bf(a[1]); o[2] = f2bf(a[2]); o[3] = f2bf(a[3]);
        o[4] = f2bf(b[0]); o[5] = f2bf(b[1]); o[6] = f2bf(b[2]); o[7] = f2bf(b[3]);
        *(ushort8*)(x_bf + i) = o;
    } else if (tid < NX + NW1) {
        int idx = tid - NX;
        int k = idx & 511, n = idx >> 9;
        wqkvT[n * 512 + k] = f2bf(w_qkv[k * N_QKV + n]);
    } else if (tid < NX + NW1 + NW2) {
        int idx = tid - NX - NW1;
        int k = idx & 511, n = idx >> 9;
        woutT[n * 512 + k] = f2bf(w_out[k * D_ + n]);
    }
}

// ---------------------------------------------------------------------------
// GEMM body: C[128][128] tile, A[M][K] bf16 row-major, Bt[N][K] bf16 row-major
// ---------------------------------------------------------------------------
#define LDSPAD 40

__device__ __forceinline__ void gemm_tile_128(
    const unsigned short* __restrict__ A, const unsigned short* __restrict__ Bt,
    int K, int bm, int bn,
    unsigned short* sA, unsigned short* sB, f32x4 acc[4][4])
{
    const int tid = threadIdx.x;
    const int w = tid >> 6, l = tid & 63;
    const int wr = (w >> 1) * 64, wc = (w & 1) * 64;
#pragma unroll
    for (int mi = 0; mi < 4; ++mi)
#pragma unroll
        for (int ni = 0; ni < 4; ++ni)
#pragma unroll
            for (int r = 0; r < 4; ++r) acc[mi][ni][r] = 0.f;

    for (int kt = 0; kt < K; kt += 32) {
#pragma unroll
        for (int c = 0; c < 2; ++c) {
            int chunk = tid + c * 256;
            int row = chunk >> 2;
            int col8 = (chunk & 3) * 8;
            *(ushort8*)(sA + row * LDSPAD + col8) =
                *(const ushort8*)(A + (size_t)(bm + row) * K + kt + col8);
            *(ushort8*)(sB + row * LDSPAD + col8) =
                *(const ushort8*)(Bt + (size_t)(bn + row) * K + kt + col8);
        }
        __syncthreads();
        short8 af[4], bfr[4];
#pragma unroll
        for (int i = 0; i < 4; ++i) {
            af[i]  = *(const short8*)(sA + (wr + i * 16 + (l & 15)) * LDSPAD + (l >> 4) * 8);
            bfr[i] = *(const short8*)(sB + (wc + i * 16 + (l & 15)) * LDSPAD + (l >> 4) * 8);
        }
#pragma unroll
        for (int mi = 0; mi < 4; ++mi)
#pragma unroll
            for (int ni = 0; ni < 4; ++ni)
                acc[mi][ni] = __builtin_amdgcn_mfma_f32_16x16x32_bf16(
                    af[mi], bfr[ni], acc[mi][ni], 0, 0, 0);
        __syncthreads();
    }
}

__global__ __launch_bounds__(256) void gemm_qkv_kernel(
    const unsigned short* __restrict__ A, const unsigned short* __restrict__ Bt,
    unsigned short* __restrict__ qkv)
{
    __shared__ __align__(16) unsigned short sA[128 * LDSPAD];
    __shared__ __align__(16) unsigned short sB[128 * LDSPAD];
    f32x4 acc[4][4];
    int bn = blockIdx.x * 128, bm = blockIdx.y * 128;
    gemm_tile_128(A, Bt, 512, bm, bn, sA, sB, acc);
    const int l = threadIdx.x & 63, w = threadIdx.x >> 6;
    const int wr = (w >> 1) * 64, wc = (w & 1) * 64;
#pragma unroll
    for (int mi = 0; mi < 4; ++mi)
#pragma unroll
        for (int ni = 0; ni < 4; ++ni)
#pragma unroll
            for (int r = 0; r < 4; ++r) {
                int row = bm + wr + mi * 16 + (l >> 4) * 4 + r;
                int col = bn + wc + ni * 16 + (l & 15);
                float v = acc[mi][ni][r];
                if (col < D_) v *= QSCALE_;   // scale+log2e folded into Q
                qkv[(size_t)row * N_QKV + col] = f2bf(v);
            }
}

__global__ __launch_bounds__(256) void gemm_out_kernel(
    const unsigned short* __restrict__ A, const unsigned short* __restrict__ Bt,
    const float* __restrict__ b_out, const float* __restrict__ m,
    float* __restrict__ out)
{
    __shared__ __align__(16) unsigned short sA[128 * LDSPAD];
    __shared__ __align__(16) unsigned short sB[128 * LDSPAD];
    f32x4 acc[4][4];
    int bn = blockIdx.x * 128, bm = blockIdx.y * 128;
    gemm_tile_128(A, Bt, 512, bm, bn, sA, sB, acc);
    const int l = threadIdx.x & 63, w = threadIdx.x >> 6;
    const int wr = (w >> 1) * 64, wc = (w & 1) * 64;
#pragma unroll
    for (int mi = 0; mi < 4; ++mi)
#pragma unroll
        for (int ni = 0; ni < 4; ++ni)
#pragma unroll
            for (int r = 0; r < 4; ++r) {
                int row = bm + wr + mi * 16 + (l >> 4) * 4 + r;
                int col = bn + wc + ni * 16 + (l & 15);
                out[(size_t)row * D_ + col] = (acc[mi][ni][r] + b_out[col]) * m[row];
            }
}

// ---------------------------------------------------------------------------
// V transpose: qkv V-part [b,t,h,d] -> vT[bh][d][t]  (once, outside hot loop)
// ---------------------------------------------------------------------------
__global__ __launch_bounds__(256) void vtrans_kernel(
    const unsigned short* __restrict__ qkv, unsigned short* __restrict__ vT)
{
    __shared__ __align__(16) unsigned short sT[64 * 72];
    const int bh = blockIdx.y, bb = bh >> 3, h = bh & 7;
    const int j0 = blockIdx.x * 64;
    {
        int row = threadIdx.x >> 2, c16 = (threadIdx.x & 3) * 16;
        const unsigned short* src = qkv + (size_t)(bb * T_ + j0 + row) * N_QKV + 1024 + h * 64 + c16;
        *(ushort8*)(sT + row * 72 + c16)     = *(const ushort8*)src;
        *(ushort8*)(sT + row * 72 + c16 + 8) = *(const ushort8*)(src + 8);
    }
    __syncthreads();
    int d = threadIdx.x >> 2, c = threadIdx.x & 3;
    ushort8 o0, o1;
#pragma unroll
    for (int e = 0; e < 8; ++e) o0[e] = sT[(c * 16 + e) * 72 + d];
#pragma unroll
    for (int e = 0; e < 8; ++e) o1[e] = sT[(c * 16 + 8 + e) * 72 + d];
    size_t dst = (size_t)(bh * 64 + d) * T_ + j0 + c * 16;
    *(ushort8*)(vT + dst)     = o0;
    *(ushort8*)(vT + dst + 8) = o1;
}

// ---------------------------------------------------------------------------
// Flash attention. One block = one (b,h), TWO Q-tiles {i, 31-i} (work balance:
// every block does exactly 33 KV steps). 4 waves x 16 Q-rows. Online softmax
// in log2 domain (Q pre-scaled by log2e/8). V^T pre-transposed -> vector stage.
// ---------------------------------------------------------------------------
__global__ __launch_bounds__(256) void attn_kernel(
    const unsigned short* __restrict__ qkv, const unsigned short* __restrict__ vT,
    const float* __restrict__ m, unsigned short* __restrict__ o_bf)
{
    __shared__ __align__(16) unsigned short sK[64 * 72];   // [j][d]
    __shared__ __align__(16) unsigned short sV[64 * 72];   // [d][j]
    __shared__ __align__(16) unsigned short sP[4][16 * 72];
    __shared__ float sBias[64];

    const int tid = threadIdx.x, w = tid >> 6, l = tid & 63;
    const int bh = blockIdx.y, bb = bh >> 3, h = bh & 7;

#pragma unroll 1
    for (int half = 0; half < 2; ++half) {
        const int q = half ? (31 - (int)blockIdx.x) : (int)blockIdx.x;
        const int qb = q * 64;
        const int qrow = qb + w * 16 + (l & 15);
        const int ib = qb + w * 16 + (l >> 4) * 4;   // first of this lane's 4 rows

        short8 aq[2];
#pragma unroll
        for (int kk = 0; kk < 2; ++kk)
            aq[kk] = *(const short8*)(qkv + (size_t)(bb * T_ + qrow) * N_QKV
                                      + h * 64 + kk * 32 + (l >> 4) * 8);

        f32x4 oacc[4];
        float mrun[4], lrun[4];
#pragma unroll
        for (int r = 0; r < 4; ++r) {
            mrun[r] = -1e30f; lrun[r] = 0.f;
            oacc[r][0] = 0.f; oacc[r][1] = 0.f; oacc[r][2] = 0.f; oacc[r][3] = 0.f;
        }

#pragma unroll 1
        for (int jt = 0; jt <= q; ++jt) {
            const int j0 = jt * 64;
            {   // stage: K rows, V^T rows (both vectorized), padding bias
                int row = tid >> 2;
                int c16 = (tid & 3) * 16;
                const unsigned short* kg = qkv + (size_t)(bb * T_ + j0 + row) * N_QKV + 512 + h * 64 + c16;
                *(ushort8*)(sK + row * 72 + c16)     = *(const ushort8*)kg;
                *(ushort8*)(sK + row * 72 + c16 + 8) = *(const ushort8*)(kg + 8);
                const unsigned short* vg = vT + (size_t)(bh * 64 + row) * T_ + j0 + c16;
                *(ushort8*)(sV + row * 72 + c16)     = *(const ushort8*)vg;
                *(ushort8*)(sV + row * 72 + c16 + 8) = *(const ushort8*)(vg + 8);
                if (tid < 64) sBias[tid] = (m[bb * T_ + j0 + tid] != 0.f) ? 0.f : -1e30f;
            }
            __syncthreads();

            // S = Q K^T
            f32x4 s[4];
#pragma unroll
            for (int f = 0; f < 4; ++f) {
                f32x4 sacc = {0.f, 0.f, 0.f, 0.f};
#pragma unroll
                for (int kk = 0; kk < 2; ++kk) {
                    short8 bk = *(const short8*)(sK + (f * 16 + (l & 15)) * 72 + kk * 32 + (l >> 4) * 8);
                    sacc = __builtin_amdgcn_mfma_f32_16x16x32_bf16(aq[kk], bk, sacc, 0, 0, 0);
                }
                s[f] = sacc;
            }

            // mask: padding bias always; causal compare only on diagonal tile
            if (jt == q) {
#pragma unroll
                for (int f = 0; f < 4; ++f) {
                    float bias = sBias[f * 16 + (l & 15)];
                    int jg = j0 + f * 16 + (l & 15);
#pragma unroll
                    for (int r = 0; r < 4; ++r)
                        s[f][r] = (jg > ib + r) ? -1e30f : s[f][r] + bias;
                }
            } else {
#pragma unroll
                for (int f = 0; f < 4; ++f) {
                    float bias = sBias[f * 16 + (l & 15)];
#pragma unroll
                    for (int r = 0; r < 4; ++r) s[f][r] += bias;
                }
            }

            // online softmax, log2 domain; row's 64 keys live in a 16-lane group
            float mnew[4], scl[4], ls[4];
#pragma unroll
            for (int r = 0; r < 4; ++r) {
                float v = fmaxf(fmaxf(s[0][r], s[1][r]), fmaxf(s[2][r], s[3][r]));
#pragma unroll
                for (int off = 1; off < 16; off <<= 1) v = fmaxf(v, __shfl_xor(v, off, 64));
                mnew[r] = fmaxf(mrun[r], v);
                scl[r] = __builtin_amdgcn_exp2f(mrun[r] - mnew[r]);
                mrun[r] = mnew[r];
                ls[r] = 0.f;
            }
#pragma unroll
            for (int f = 0; f < 4; ++f)
#pragma unroll
                for (int r = 0; r < 4; ++r) {
                    float p = __builtin_amdgcn_exp2f(s[f][r] - mnew[r]);
                    s[f][r] = p;
                    ls[r] += p;
                }
#pragma unroll
            for (int r = 0; r < 4; ++r) {
                float v = ls[r];
#pragma unroll
                for (int off = 1; off < 16; off <<= 1) v += __shfl_xor(v, off, 64);
                lrun[r] = lrun[r] * scl[r] + v;
            }
#pragma unroll
            for (int fd = 0; fd < 4; ++fd)
#pragma unroll
                for (int r = 0; r < 4; ++r) oacc[fd][r] *= scl[r];

            // P -> LDS (per-wave region), then PV
#pragma unroll
            for (int f = 0; f < 4; ++f)
#pragma unroll
                for (int r = 0; r < 4; ++r)
                    sP[w][((l >> 4) * 4 + r) * 72 + f * 16 + (l & 15)] = f2bf(s[f][r]);
            asm volatile("s_waitcnt lgkmcnt(0)" ::: "memory");

            short8 pa[2];
#pragma unroll
            for (int kk = 0; kk < 2; ++kk)
                pa[kk] = *(const short8*)(sP[w] + (l & 15) * 72 + kk * 32 + (l >> 4) * 8);
#pragma unroll
            for (int fd = 0; fd < 4; ++fd)
#pragma unroll
                for (int kk = 0; kk < 2; ++kk) {
                    short8 bv = *(const short8*)(sV + (fd * 16 + (l & 15)) * 72 + kk * 32 + (l >> 4) * 8);
                    oacc[fd] = __builtin_amdgcn_mfma_f32_16x16x32_bf16(pa[kk], bv, oacc[fd], 0, 0, 0);
                }
            __syncthreads();
        }

        // epilogue: O / l -> bf16 [8192][512]
#pragma unroll
        for (int fd = 0; fd < 4; ++fd)
#pragma unroll
            for (int r = 0; r < 4; ++r) {
                int rg = qb + w * 16 + (l >> 4) * 4 + r;
                float v = (lrun[r] > 0.f) ? oacc[fd][r] / lrun[r] : 0.f;
                o_bf[(size_t)(bb * T_ + rg) * D_ + h * 64 + fd * 16 + (l & 15)] = f2bf(v);
            }
    }
}

// ---------------------------------------------------------------------------
extern "C" void kernel_launch(void* const* d_in, const int* in_sizes, int n_in,
                              void* d_out, int out_size, void* d_ws, size_t ws_size,
                              hipStream_t stream)
{
    const float* x     = (const float*)d_in[0];
    const float* m     = (const float*)d_in[1];
    const float* w_qkv = (const float*)d_in[2];
    const float* w_out = (const float*)d_in[3];
    const float* b_out = (const float*)d_in[4];
    float* out = (float*)d_out;

    char* ws = (char*)d_ws;
    unsigned short* x_bf   = (unsigned short*)(ws);                 // 8 MB (reused as vT)
    unsigned short* wqkvT  = (unsigned short*)(ws + 8388608);       // 1.5 MB
    unsigned short* woutT  = (unsigned short*)(ws + 9961472);       // 0.5 MB
    unsigned short* qkv_bf = (unsigned short*)(ws + 10485760);      // 24 MB
    unsigned short* o_bf   = (unsigned short*)(ws + 35651584);      // 8 MB
    unsigned short* vT     = x_bf;  // x_bf is dead after gemm_qkv; alias it

    hipLaunchKernelGGL(prep_kernel, dim3(6144), dim3(256), 0, stream,
                       x, w_qkv, w_out, x_bf, wqkvT, woutT);
    hipLaunchKernelGGL(gemm_qkv_kernel, dim3(12, 64), dim3(256), 0, stream,
                       x_bf, wqkvT, qkv_bf);
    hipLaunchKernelGGL(vtrans_kernel, dim3(32, 32), dim3(256), 0, stream,
                       qkv_bf, vT);
    hipLaunchKernelGGL(attn_kernel, dim3(16, 32), dim3(256), 0, stream,
                       qkv_bf, vT, m, o_bf);
    hipLaunchKernelGGL(gemm_out_kernel, dim3(4, 64), dim3(256), 0, stream,
                       o_bf, woutT, b_out, m, out);
}

// Round 3
// 122.372 us; speedup vs baseline: 1.5615x; 1.2620x over previous
//
#include <hip/hip_runtime.h>
#include <hip/hip_bf16.h>
#include <stdint.h>

#define B_ 4
#define T_ 2048
#define D_ 512
#define H_ 8
#define DH_ 64
#define M_TOT (B_*T_)     // 8192
#define N_QKV (3*D_)      // 1536
// 0.125 * log2(e): folds softmax scale and exp->exp2 conversion into Q
#define QSCALE_ 0.18033688011112043f

typedef __attribute__((ext_vector_type(8))) short short8;
typedef __attribute__((ext_vector_type(8))) unsigned short ushort8;
typedef __attribute__((ext_vector_type(4))) unsigned short ushort4_t;
typedef __attribute__((ext_vector_type(2))) unsigned int uint2_t;
typedef __attribute__((ext_vector_type(4))) float f32x4;

static __device__ __forceinline__ unsigned short f2bf(float f) {
    union { float f; unsigned u; } v; v.f = f;
    unsigned r = v.u + 0x7fffu + ((v.u >> 16) & 1u);
    return (unsigned short)(r >> 16);
}

// ---------------------------------------------------------------------------
// prep: x -> bf16 (vectorized); w_qkv, w_out -> bf16 transposed [N][K]
// ---------------------------------------------------------------------------
__global__ __launch_bounds__(256) void prep_kernel(
    const float* __restrict__ x, const float* __restrict__ w_qkv,
    const float* __restrict__ w_out,
    unsigned short* __restrict__ x_bf, unsigned short* __restrict__ wqkvT,
    unsigned short* __restrict__ woutT)
{
    const int NX  = M_TOT * D_ / 8;
    const int NW1 = D_ * N_QKV;
    const int NW2 = D_ * D_;
    int tid = blockIdx.x * 256 + threadIdx.x;
    if (tid < NX) {
        int i = tid * 8;
        f32x4 a = *(const f32x4*)(x + i);
        f32x4 b = *(const f32x4*)(x + i + 4);
        ushort8 o;
        o[0] = f2bf(a[0]); o[1] = f2bf(a[1]); o[2] = f2bf(a[2]); o[3] = f2bf(a[3]);
        o[4] = f2bf(b[0]); o[5] = f2bf(b[1]); o[6] = f2bf(b[2]); o[7] = f2bf(b[3]);
        *(ushort8*)(x_bf + i) = o;
    } else if (tid < NX + NW1) {
        int idx = tid - NX;
        int k = idx & 511, n = idx >> 9;
        wqkvT[n * 512 + k] = f2bf(w_qkv[k * N_QKV + n]);
    } else if (tid < NX + NW1 + NW2) {
        int idx = tid - NX - NW1;
        int k = idx & 511, n = idx >> 9;
        woutT[n * 512 + k] = f2bf(w_out[k * D_ + n]);
    }
}

// ---------------------------------------------------------------------------
// GEMM body: C[128][128] tile, A[M][K] bf16 row-major, Bt[N][K] bf16 row-major
// ---------------------------------------------------------------------------
#define LDSPAD 40

__device__ __forceinline__ void gemm_tile_128(
    const unsigned short* __restrict__ A, const unsigned short* __restrict__ Bt,
    int K, int bm, int bn,
    unsigned short* sA, unsigned short* sB, f32x4 acc[4][4])
{
    const int tid = threadIdx.x;
    const int w = tid >> 6, l = tid & 63;
    const int wr = (w >> 1) * 64, wc = (w & 1) * 64;
#pragma unroll
    for (int mi = 0; mi < 4; ++mi)
#pragma unroll
        for (int ni = 0; ni < 4; ++ni)
#pragma unroll
            for (int r = 0; r < 4; ++r) acc[mi][ni][r] = 0.f;

    for (int kt = 0; kt < K; kt += 32) {
#pragma unroll
        for (int c = 0; c < 2; ++c) {
            int chunk = tid + c * 256;
            int row = chunk >> 2;
            int col8 = (chunk & 3) * 8;
            *(ushort8*)(sA + row * LDSPAD + col8) =
                *(const ushort8*)(A + (size_t)(bm + row) * K + kt + col8);
            *(ushort8*)(sB + row * LDSPAD + col8) =
                *(const ushort8*)(Bt + (size_t)(bn + row) * K + kt + col8);
        }
        __syncthreads();
        short8 af[4], bfr[4];
#pragma unroll
        for (int i = 0; i < 4; ++i) {
            af[i]  = *(const short8*)(sA + (wr + i * 16 + (l & 15)) * LDSPAD + (l >> 4) * 8);
            bfr[i] = *(const short8*)(sB + (wc + i * 16 + (l & 15)) * LDSPAD + (l >> 4) * 8);
        }
#pragma unroll
        for (int mi = 0; mi < 4; ++mi)
#pragma unroll
            for (int ni = 0; ni < 4; ++ni)
                acc[mi][ni] = __builtin_amdgcn_mfma_f32_16x16x32_bf16(
                    af[mi], bfr[ni], acc[mi][ni], 0, 0, 0);
        __syncthreads();
    }
}

// gemm_qkv with fused epilogue: Q cols scaled -> qkv; K cols -> qkv;
// V cols written TRANSPOSED to vT[bh][d][t] (packed b64), not to qkv.
__global__ __launch_bounds__(256) void gemm_qkv_kernel(
    const unsigned short* __restrict__ A, const unsigned short* __restrict__ Bt,
    unsigned short* __restrict__ qkv, unsigned short* __restrict__ vT)
{
    __shared__ __align__(16) unsigned short sA[128 * LDSPAD];
    __shared__ __align__(16) unsigned short sB[128 * LDSPAD];
    f32x4 acc[4][4];
    int bn = blockIdx.x * 128, bm = blockIdx.y * 128;
    gemm_tile_128(A, Bt, 512, bm, bn, sA, sB, acc);
    const int l = threadIdx.x & 63, w = threadIdx.x >> 6;
    const int wr = (w >> 1) * 64, wc = (w & 1) * 64;
    if (bn < 1024) {   // Q or K third -> qkv buffer
        bool isQ = (bn < 512);
#pragma unroll
        for (int mi = 0; mi < 4; ++mi)
#pragma unroll
            for (int ni = 0; ni < 4; ++ni)
#pragma unroll
                for (int r = 0; r < 4; ++r) {
                    int row = bm + wr + mi * 16 + (l >> 4) * 4 + r;
                    int col = bn + wc + ni * 16 + (l & 15);
                    float v = acc[mi][ni][r];
                    if (isQ) v *= QSCALE_;
                    qkv[(size_t)row * N_QKV + col] = f2bf(v);
                }
    } else {           // V third -> vT[bh][d][t], 4 consecutive t packed
#pragma unroll
        for (int mi = 0; mi < 4; ++mi)
#pragma unroll
            for (int ni = 0; ni < 4; ++ni) {
                int row0 = bm + wr + mi * 16 + (l >> 4) * 4;
                int dall = bn - 1024 + wc + ni * 16 + (l & 15);
                int hh = dall >> 6, d = dall & 63;
                int b = row0 >> 11, t0 = row0 & 2047;
                ushort4_t vv;
#pragma unroll
                for (int r = 0; r < 4; ++r) vv[r] = f2bf(acc[mi][ni][r]);
                *(ushort4_t*)(vT + ((size_t)((b * 8 + hh) * 64 + d)) * T_ + t0) = vv;
            }
    }
}

__global__ __launch_bounds__(256) void gemm_out_kernel(
    const unsigned short* __restrict__ A, const unsigned short* __restrict__ Bt,
    const float* __restrict__ b_out, const float* __restrict__ m,
    float* __restrict__ out)
{
    __shared__ __align__(16) unsigned short sA[128 * LDSPAD];
    __shared__ __align__(16) unsigned short sB[128 * LDSPAD];
    f32x4 acc[4][4];
    int bn = blockIdx.x * 128, bm = blockIdx.y * 128;
    gemm_tile_128(A, Bt, 512, bm, bn, sA, sB, acc);
    const int l = threadIdx.x & 63, w = threadIdx.x >> 6;
    const int wr = (w >> 1) * 64, wc = (w & 1) * 64;
#pragma unroll
    for (int mi = 0; mi < 4; ++mi)
#pragma unroll
        for (int ni = 0; ni < 4; ++ni)
#pragma unroll
            for (int r = 0; r < 4; ++r) {
                int row = bm + wr + mi * 16 + (l >> 4) * 4 + r;
                int col = bn + wc + ni * 16 + (l & 15);
                out[(size_t)row * D_ + col] = (acc[mi][ni][r] + b_out[col]) * m[row];
            }
}

// ---------------------------------------------------------------------------
// Flash attention, swapped-QK layout: lane owns q-row i = lane&15; S^T frags
// give 16 P-values/lane -> in-lane softmax + 2 shfl_xor. PV via mfma(V^T, P)
// -> O^T, stats stay lane-local. Paired Q-tiles {i, 31-i} for balance.
// ---------------------------------------------------------------------------
__global__ __launch_bounds__(256) void attn_kernel(
    const unsigned short* __restrict__ qkv, const unsigned short* __restrict__ vT,
    const float* __restrict__ m, unsigned short* __restrict__ o_bf)
{
    __shared__ __align__(16) unsigned short sK[64 * 72];   // [j][d]
    __shared__ __align__(16) unsigned short sV[64 * 72];   // [d][j] (V^T rows)
    __shared__ __align__(16) unsigned short sP[4][16 * 72];
    __shared__ __align__(16) float sBias[64];

    const int tid = threadIdx.x, w = tid >> 6, l = tid & 63;
    const int i16 = l & 15, g = l >> 4;
    const int bh = blockIdx.y, bb = bh >> 3, h = bh & 7;

#pragma unroll 1
    for (int half = 0; half < 2; ++half) {
        const int q = half ? (31 - (int)blockIdx.x) : (int)blockIdx.x;
        const int qb = q * 64;
        const int qrow = qb + w * 16 + i16;      // this lane's q-row (global i)

        short8 bq[2];
#pragma unroll
        for (int kk = 0; kk < 2; ++kk)
            bq[kk] = *(const short8*)(qkv + (size_t)(bb * T_ + qrow) * N_QKV
                                      + h * 64 + kk * 32 + g * 8);

        f32x4 oacc[4];
        float mrun = -1e30f, lrun = 0.f;
#pragma unroll
        for (int fd = 0; fd < 4; ++fd) {
            oacc[fd][0] = 0.f; oacc[fd][1] = 0.f; oacc[fd][2] = 0.f; oacc[fd][3] = 0.f;
        }

#pragma unroll 1
        for (int jt = 0; jt <= q; ++jt) {
            const int j0 = jt * 64;
            {   // stage K rows + V^T rows (vectorized) + padding bias
                int row = tid >> 2;
                int c16 = (tid & 3) * 16;
                const unsigned short* kg = qkv + (size_t)(bb * T_ + j0 + row) * N_QKV + 512 + h * 64 + c16;
                *(ushort8*)(sK + row * 72 + c16)     = *(const ushort8*)kg;
                *(ushort8*)(sK + row * 72 + c16 + 8) = *(const ushort8*)(kg + 8);
                const unsigned short* vg = vT + (size_t)(bh * 64 + row) * T_ + j0 + c16;
                *(ushort8*)(sV + row * 72 + c16)     = *(const ushort8*)vg;
                *(ushort8*)(sV + row * 72 + c16 + 8) = *(const ushort8*)(vg + 8);
                if (tid < 64) sBias[tid] = (m[bb * T_ + j0 + tid] != 0.f) ? 0.f : -1e30f;
            }
            __syncthreads();

            // S^T = K Q^T : lane holds S[j = j0+16f+4g+r][i = qrow]
            f32x4 s[4];
            __builtin_amdgcn_s_setprio(1);
#pragma unroll
            for (int f = 0; f < 4; ++f) {
                f32x4 sacc = {0.f, 0.f, 0.f, 0.f};
#pragma unroll
                for (int kk = 0; kk < 2; ++kk) {
                    short8 ka = *(const short8*)(sK + (f * 16 + i16) * 72 + kk * 32 + g * 8);
                    sacc = __builtin_amdgcn_mfma_f32_16x16x32_bf16(ka, bq[kk], sacc, 0, 0, 0);
                }
                s[f] = sacc;
            }
            __builtin_amdgcn_s_setprio(0);

            // masks: padding bias always; causal compare only on diagonal tile
            if (jt == q) {
#pragma unroll
                for (int f = 0; f < 4; ++f) {
                    f32x4 bias4 = *(const f32x4*)(sBias + f * 16 + g * 4);
#pragma unroll
                    for (int r = 0; r < 4; ++r) {
                        int jg = j0 + f * 16 + g * 4 + r;
                        s[f][r] = (jg > qrow) ? -1e30f : s[f][r] + bias4[r];
                    }
                }
            } else {
#pragma unroll
                for (int f = 0; f < 4; ++f) {
                    f32x4 bias4 = *(const f32x4*)(sBias + f * 16 + g * 4);
#pragma unroll
                    for (int r = 0; r < 4; ++r) s[f][r] += bias4[r];
                }
            }

            // per-lane online softmax: 16 in-lane values + 2 cross-lane ops
            float pm = -1e30f;
#pragma unroll
            for (int f = 0; f < 4; ++f)
#pragma unroll
                for (int r = 0; r < 4; ++r) pm = fmaxf(pm, s[f][r]);
            pm = fmaxf(pm, __shfl_xor(pm, 16, 64));
            pm = fmaxf(pm, __shfl_xor(pm, 32, 64));
            float mnew = fmaxf(mrun, pm);
            float scl = __builtin_amdgcn_exp2f(mrun - mnew);
            mrun = mnew;
            float ls = 0.f;
#pragma unroll
            for (int f = 0; f < 4; ++f)
#pragma unroll
                for (int r = 0; r < 4; ++r) {
                    float p = __builtin_amdgcn_exp2f(s[f][r] - mnew);
                    s[f][r] = p;
                    ls += p;
                }
            ls += __shfl_xor(ls, 16, 64);
            ls += __shfl_xor(ls, 32, 64);
            lrun = lrun * scl + ls;
#pragma unroll
            for (int fd = 0; fd < 4; ++fd)
#pragma unroll
                for (int r = 0; r < 4; ++r) oacc[fd][r] *= scl;

            // pack P (bf16 pairs) -> sP row i16, quad column 4g+16f (b64 writes)
#pragma unroll
            for (int f = 0; f < 4; ++f) {
                unsigned int w0, w1;
                asm("v_cvt_pk_bf16_f32 %0, %1, %2" : "=v"(w0) : "v"(s[f][0]), "v"(s[f][1]));
                asm("v_cvt_pk_bf16_f32 %0, %1, %2" : "=v"(w1) : "v"(s[f][2]), "v"(s[f][3]));
                uint2_t dw; dw[0] = w0; dw[1] = w1;
                *(uint2_t*)(sP[w] + i16 * 72 + f * 16 + g * 4) = dw;
            }
            asm volatile("s_waitcnt lgkmcnt(0)" ::: "memory");

            short8 pb[2];
#pragma unroll
            for (int kk = 0; kk < 2; ++kk)
                pb[kk] = *(const short8*)(sP[w] + i16 * 72 + kk * 32 + g * 8);

            __builtin_amdgcn_s_setprio(1);
#pragma unroll
            for (int fd = 0; fd < 4; ++fd)
#pragma unroll
                for (int kk = 0; kk < 2; ++kk) {
                    short8 va = *(const short8*)(sV + (fd * 16 + i16) * 72 + kk * 32 + g * 8);
                    oacc[fd] = __builtin_amdgcn_mfma_f32_16x16x32_bf16(va, pb[kk], oacc[fd], 0, 0, 0);
                }
            __builtin_amdgcn_s_setprio(0);
            __syncthreads();
        }

        // epilogue: lane holds O^T[d = fd*16+4g+r][i = qrow]; pack 4 d's -> b64
        float rinv = (lrun > 0.f) ? 1.0f / lrun : 0.f;
#pragma unroll
        for (int fd = 0; fd < 4; ++fd) {
            ushort4_t o4;
#pragma unroll
            for (int r = 0; r < 4; ++r) o4[r] = f2bf(oacc[fd][r] * rinv);
            *(ushort4_t*)(o_bf + (size_t)(bb * T_ + qrow) * D_ + h * 64 + fd * 16 + g * 4) = o4;
        }
    }
}

// ---------------------------------------------------------------------------
extern "C" void kernel_launch(void* const* d_in, const int* in_sizes, int n_in,
                              void* d_out, int out_size, void* d_ws, size_t ws_size,
                              hipStream_t stream)
{
    const float* x     = (const float*)d_in[0];
    const float* m     = (const float*)d_in[1];
    const float* w_qkv = (const float*)d_in[2];
    const float* w_out = (const float*)d_in[3];
    const float* b_out = (const float*)d_in[4];
    float* out = (float*)d_out;

    char* ws = (char*)d_ws;
    unsigned short* x_bf   = (unsigned short*)(ws);                 // 8 MB
    unsigned short* wqkvT  = (unsigned short*)(ws + 8388608);       // 1.5 MB
    unsigned short* woutT  = (unsigned short*)(ws + 9961472);       // 0.5 MB
    unsigned short* qkv_bf = (unsigned short*)(ws + 10485760);      // 24 MB (Q,K used; V third unused)
    unsigned short* o_bf   = (unsigned short*)(ws + 35651584);      // 8 MB
    // vT lives in d_out's first 8 MB: dead until gemm_out, which overwrites all of d_out.
    unsigned short* vT     = (unsigned short*)d_out;                // [32][64][2048] bf16

    hipLaunchKernelGGL(prep_kernel, dim3(6144), dim3(256), 0, stream,
                       x, w_qkv, w_out, x_bf, wqkvT, woutT);
    hipLaunchKernelGGL(gemm_qkv_kernel, dim3(12, 64), dim3(256), 0, stream,
                       x_bf, wqkvT, qkv_bf, vT);
    hipLaunchKernelGGL(attn_kernel, dim3(16, 32), dim3(256), 0, stream,
                       qkv_bf, vT, m, o_bf);
    hipLaunchKernelGGL(gemm_out_kernel, dim3(4, 64), dim3(256), 0, stream,
                       o_bf, woutT, b_out, m, out);
}

// Round 4
// 112.405 us; speedup vs baseline: 1.7000x; 1.0887x over previous
//
#include <hip/hip_runtime.h>
#include <hip/hip_bf16.h>
#include <stdint.h>

#define B_ 4
#define T_ 2048
#define D_ 512
#define H_ 8
#define DH_ 64
#define M_TOT (B_*T_)     // 8192
#define N_QKV (3*D_)      // 1536
// 0.125 * log2(e): folds softmax scale and exp->exp2 conversion into Q
#define QSCALE_ 0.18033688011112043f

typedef __attribute__((ext_vector_type(8))) short short8;
typedef __attribute__((ext_vector_type(8))) unsigned short ushort8;
typedef __attribute__((ext_vector_type(4))) unsigned short ushort4_t;
typedef __attribute__((ext_vector_type(4))) float f32x4;
typedef __attribute__((ext_vector_type(16))) float f32x16;

#define MFMA32(a,b,c) __builtin_amdgcn_mfma_f32_32x32x16_bf16(a,b,c,0,0,0)

static __device__ __forceinline__ unsigned short f2bf(float f) {
    union { float f; unsigned u; } v; v.f = f;
    unsigned r = v.u + 0x7fffu + ((v.u >> 16) & 1u);
    return (unsigned short)(r >> 16);
}

// ---------------------------------------------------------------------------
// prep: x -> bf16 (vectorized); w_qkv, w_out -> bf16 transposed [N][K]
// ---------------------------------------------------------------------------
__global__ __launch_bounds__(256) void prep_kernel(
    const float* __restrict__ x, const float* __restrict__ w_qkv,
    const float* __restrict__ w_out,
    unsigned short* __restrict__ x_bf, unsigned short* __restrict__ wqkvT,
    unsigned short* __restrict__ woutT)
{
    const int NX  = M_TOT * D_ / 8;
    const int NW1 = D_ * N_QKV;
    const int NW2 = D_ * D_;
    int tid = blockIdx.x * 256 + threadIdx.x;
    if (tid < NX) {
        int i = tid * 8;
        f32x4 a = *(const f32x4*)(x + i);
        f32x4 b = *(const f32x4*)(x + i + 4);
        ushort8 o;
        o[0] = f2bf(a[0]); o[1] = f2bf(a[1]); o[2] = f2bf(a[2]); o[3] = f2bf(a[3]);
        o[4] = f2bf(b[0]); o[5] = f2bf(b[1]); o[6] = f2bf(b[2]); o[7] = f2bf(b[3]);
        *(ushort8*)(x_bf + i) = o;
    } else if (tid < NX + NW1) {
        int idx = tid - NX;
        int k = idx & 511, n = idx >> 9;
        wqkvT[n * 512 + k] = f2bf(w_qkv[k * N_QKV + n]);
    } else if (tid < NX + NW1 + NW2) {
        int idx = tid - NX - NW1;
        int k = idx & 511, n = idx >> 9;
        woutT[n * 512 + k] = f2bf(w_out[k * D_ + n]);
    }
}

// ---------------------------------------------------------------------------
// GEMM body (unchanged this round)
// ---------------------------------------------------------------------------
#define LDSPAD 40

__device__ __forceinline__ void gemm_tile_128(
    const unsigned short* __restrict__ A, const unsigned short* __restrict__ Bt,
    int K, int bm, int bn,
    unsigned short* sA, unsigned short* sB, f32x4 acc[4][4])
{
    const int tid = threadIdx.x;
    const int w = tid >> 6, l = tid & 63;
    const int wr = (w >> 1) * 64, wc = (w & 1) * 64;
#pragma unroll
    for (int mi = 0; mi < 4; ++mi)
#pragma unroll
        for (int ni = 0; ni < 4; ++ni)
#pragma unroll
            for (int r = 0; r < 4; ++r) acc[mi][ni][r] = 0.f;

    for (int kt = 0; kt < K; kt += 32) {
#pragma unroll
        for (int c = 0; c < 2; ++c) {
            int chunk = tid + c * 256;
            int row = chunk >> 2;
            int col8 = (chunk & 3) * 8;
            *(ushort8*)(sA + row * LDSPAD + col8) =
                *(const ushort8*)(A + (size_t)(bm + row) * K + kt + col8);
            *(ushort8*)(sB + row * LDSPAD + col8) =
                *(const ushort8*)(Bt + (size_t)(bn + row) * K + kt + col8);
        }
        __syncthreads();
        short8 af[4], bfr[4];
#pragma unroll
        for (int i = 0; i < 4; ++i) {
            af[i]  = *(const short8*)(sA + (wr + i * 16 + (l & 15)) * LDSPAD + (l >> 4) * 8);
            bfr[i] = *(const short8*)(sB + (wc + i * 16 + (l & 15)) * LDSPAD + (l >> 4) * 8);
        }
#pragma unroll
        for (int mi = 0; mi < 4; ++mi)
#pragma unroll
            for (int ni = 0; ni < 4; ++ni)
                acc[mi][ni] = __builtin_amdgcn_mfma_f32_16x16x32_bf16(
                    af[mi], bfr[ni], acc[mi][ni], 0, 0, 0);
        __syncthreads();
    }
}

__global__ __launch_bounds__(256) void gemm_qkv_kernel(
    const unsigned short* __restrict__ A, const unsigned short* __restrict__ Bt,
    unsigned short* __restrict__ qkv, unsigned short* __restrict__ vT)
{
    __shared__ __align__(16) unsigned short sA[128 * LDSPAD];
    __shared__ __align__(16) unsigned short sB[128 * LDSPAD];
    f32x4 acc[4][4];
    int bn = blockIdx.x * 128, bm = blockIdx.y * 128;
    gemm_tile_128(A, Bt, 512, bm, bn, sA, sB, acc);
    const int l = threadIdx.x & 63, w = threadIdx.x >> 6;
    const int wr = (w >> 1) * 64, wc = (w & 1) * 64;
    if (bn < 1024) {
        bool isQ = (bn < 512);
#pragma unroll
        for (int mi = 0; mi < 4; ++mi)
#pragma unroll
            for (int ni = 0; ni < 4; ++ni)
#pragma unroll
                for (int r = 0; r < 4; ++r) {
                    int row = bm + wr + mi * 16 + (l >> 4) * 4 + r;
                    int col = bn + wc + ni * 16 + (l & 15);
                    float v = acc[mi][ni][r];
                    if (isQ) v *= QSCALE_;
                    qkv[(size_t)row * N_QKV + col] = f2bf(v);
                }
    } else {
#pragma unroll
        for (int mi = 0; mi < 4; ++mi)
#pragma unroll
            for (int ni = 0; ni < 4; ++ni) {
                int row0 = bm + wr + mi * 16 + (l >> 4) * 4;
                int dall = bn - 1024 + wc + ni * 16 + (l & 15);
                int hh = dall >> 6, d = dall & 63;
                int b = row0 >> 11, t0 = row0 & 2047;
                ushort4_t vv;
#pragma unroll
                for (int r = 0; r < 4; ++r) vv[r] = f2bf(acc[mi][ni][r]);
                *(ushort4_t*)(vT + ((size_t)((b * 8 + hh) * 64 + d)) * T_ + t0) = vv;
            }
    }
}

__global__ __launch_bounds__(256) void gemm_out_kernel(
    const unsigned short* __restrict__ A, const unsigned short* __restrict__ Bt,
    const float* __restrict__ b_out, const float* __restrict__ m,
    float* __restrict__ out)
{
    __shared__ __align__(16) unsigned short sA[128 * LDSPAD];
    __shared__ __align__(16) unsigned short sB[128 * LDSPAD];
    f32x4 acc[4][4];
    int bn = blockIdx.x * 128, bm = blockIdx.y * 128;
    gemm_tile_128(A, Bt, 512, bm, bn, sA, sB, acc);
    const int l = threadIdx.x & 63, w = threadIdx.x >> 6;
    const int wr = (w >> 1) * 64, wc = (w & 1) * 64;
#pragma unroll
    for (int mi = 0; mi < 4; ++mi)
#pragma unroll
        for (int ni = 0; ni < 4; ++ni)
#pragma unroll
            for (int r = 0; r < 4; ++r) {
                int row = bm + wr + mi * 16 + (l >> 4) * 4 + r;
                int col = bn + wc + ni * 16 + (l & 15);
                out[(size_t)row * D_ + col] = (acc[mi][ni][r] + b_out[col]) * m[row];
            }
}

// ---------------------------------------------------------------------------
// Flash attention, 32x32 MFMA + in-register P repack + 2-way KV split.
// Block = (b,h) x paired Q-tiles {i,31-i} of 64 rows. Waves 0,1: rows 0-31 /
// 32-63 on EVEN KV tiles; waves 2,3: same rows on ODD tiles; merge via LDS.
// K/V LDS tiles [64][64] with chunk^=(row&7) XOR swizzle (b128-conflict-free
// to the BW floor). P stays in registers: cvt_pk_bf16 + permlane32_swap.
// ---------------------------------------------------------------------------
__global__ __launch_bounds__(256) void attn_kernel(
    const unsigned short* __restrict__ qkv, const unsigned short* __restrict__ vT,
    const float* __restrict__ m, unsigned short* __restrict__ o_bf)
{
    __shared__ __align__(16) unsigned short sK[2][64 * 64];
    __shared__ __align__(16) unsigned short sV[2][64 * 64];
    __shared__ __align__(16) float sBias[2][64];
    __shared__ float sMrgO[2][64][33];     // [rowblk][lane][32 regs], +1 pad
    __shared__ float sMrgS[2][64][2];      // m, l

    const int tid = threadIdx.x, wv = tid >> 6, l = tid & 63;
    const int i31 = l & 31, hl = l >> 5;
    const int kvpar = wv >> 1;             // 0: even KV tiles, 1: odd
    const int rb = wv & 1;                 // 0: q-rows 0-31, 1: 32-63
    const int bh = blockIdx.y, bb = bh >> 3, h = bh & 7;
    const int swz = i31 & 7;               // frag-read swizzle (row&7, rows 32-apart share it)

#pragma unroll 1
    for (int half = 0; half < 2; ++half) {
        const int q = half ? (31 - (int)blockIdx.x) : (int)blockIdx.x;
        const int qb = q * 64;
        const int qrow = qb + rb * 32 + i31;

        // Q B-frags: bq[c][e] = Q[qrow][c*16 + hl*8 + e]  (pre-scaled)
        short8 bq[4];
#pragma unroll
        for (int c = 0; c < 4; ++c)
            bq[c] = *(const short8*)(qkv + (size_t)(bb * T_ + qrow) * N_QKV
                                     + h * 64 + c * 16 + hl * 8);

        f32x16 oacc0, oacc1;
#pragma unroll
        for (int rr = 0; rr < 16; ++rr) { oacc0[rr] = 0.f; oacc1[rr] = 0.f; }
        float mrun = -1e30f, lrun = 0.f;

        const int nss = (q >> 1) + 1;
#pragma unroll 1
        for (int ss = 0; ss < nss; ++ss) {
            const int jtA = 2 * ss, jtB = 2 * ss + 1;
            const bool hasB = (jtB <= q);
            {   // stage both tiles (K rows + V^T rows), XOR-swizzled chunks
                int row = tid >> 2, cg = (tid & 3) * 16;
                int cc0 = ((cg >> 3) ^ (row & 7)) * 8;
                int cc1 = (((cg >> 3) + 1) ^ (row & 7)) * 8;
                const unsigned short* kgA = qkv + (size_t)(bb * T_ + jtA * 64 + row) * N_QKV + 512 + h * 64 + cg;
                *(ushort8*)(sK[0] + row * 64 + cc0) = *(const ushort8*)kgA;
                *(ushort8*)(sK[0] + row * 64 + cc1) = *(const ushort8*)(kgA + 8);
                const unsigned short* vgA = vT + (size_t)(bh * 64 + row) * T_ + jtA * 64 + cg;
                *(ushort8*)(sV[0] + row * 64 + cc0) = *(const ushort8*)vgA;
                *(ushort8*)(sV[0] + row * 64 + cc1) = *(const ushort8*)(vgA + 8);
                if (hasB) {
                    const unsigned short* kgB = qkv + (size_t)(bb * T_ + jtB * 64 + row) * N_QKV + 512 + h * 64 + cg;
                    *(ushort8*)(sK[1] + row * 64 + cc0) = *(const ushort8*)kgB;
                    *(ushort8*)(sK[1] + row * 64 + cc1) = *(const ushort8*)(kgB + 8);
                    const unsigned short* vgB = vT + (size_t)(bh * 64 + row) * T_ + jtB * 64 + cg;
                    *(ushort8*)(sV[1] + row * 64 + cc0) = *(const ushort8*)vgB;
                    *(ushort8*)(sV[1] + row * 64 + cc1) = *(const ushort8*)(vgB + 8);
                }
                if (tid < 128) {
                    int tI = tid >> 6, jl = tid & 63;
                    if (!tI || hasB) {
                        int jt = tI ? jtB : jtA;
                        sBias[tI][jl] = (m[bb * T_ + jt * 64 + jl] != 0.f) ? 0.f : -1e30f;
                    }
                }
            }
            __syncthreads();

            const int jt = kvpar ? jtB : jtA;
            if (kvpar == 0 || hasB) {
                const int j0 = jt * 64;
                const unsigned short* sKp = sK[kvpar];
                const unsigned short* sVp = sV[kvpar];

                // S^T = K Q^T: two 32x32 C-tiles (j 0-31, 32-63)
                f32x16 s0, s1;
#pragma unroll
                for (int rr = 0; rr < 16; ++rr) { s0[rr] = 0.f; s1[rr] = 0.f; }
                __builtin_amdgcn_s_setprio(1);
#pragma unroll
                for (int c = 0; c < 4; ++c) {
                    int pc = ((2 * c + hl) ^ swz) * 8;
                    short8 ka0 = *(const short8*)(sKp + i31 * 64 + pc);
                    short8 ka1 = *(const short8*)(sKp + (32 + i31) * 64 + pc);
                    s0 = MFMA32(ka0, bq[c], s0);
                    s1 = MFMA32(ka1, bq[c], s1);
                }
                __builtin_amdgcn_s_setprio(0);

                // bias (+ causal on diagonal tile): j_local = t*32 + 8*qd + 4*hl + (rr&3)
                if (jt == q) {
#pragma unroll
                    for (int qd = 0; qd < 4; ++qd) {
                        f32x4 b0 = *(const f32x4*)(&sBias[kvpar][8 * qd + 4 * hl]);
                        f32x4 b1 = *(const f32x4*)(&sBias[kvpar][32 + 8 * qd + 4 * hl]);
#pragma unroll
                        for (int e = 0; e < 4; ++e) {
                            int jl0 = 8 * qd + 4 * hl + e;
                            s0[qd * 4 + e] = (j0 + jl0 > qrow) ? -1e30f : s0[qd * 4 + e] + b0[e];
                            s1[qd * 4 + e] = (j0 + 32 + jl0 > qrow) ? -1e30f : s1[qd * 4 + e] + b1[e];
                        }
                    }
                } else {
#pragma unroll
                    for (int qd = 0; qd < 4; ++qd) {
                        f32x4 b0 = *(const f32x4*)(&sBias[kvpar][8 * qd + 4 * hl]);
                        f32x4 b1 = *(const f32x4*)(&sBias[kvpar][32 + 8 * qd + 4 * hl]);
#pragma unroll
                        for (int e = 0; e < 4; ++e) {
                            s0[qd * 4 + e] += b0[e];
                            s1[qd * 4 + e] += b1[e];
                        }
                    }
                }

                // online softmax: 32 in-lane values + 1 cross-half exchange
                float pm = -1e30f;
#pragma unroll
                for (int rr = 0; rr < 16; ++rr) pm = fmaxf(pm, fmaxf(s0[rr], s1[rr]));
                pm = fmaxf(pm, __shfl_xor(pm, 32, 64));
                float mnew = fmaxf(mrun, pm);
                float scl = __builtin_amdgcn_exp2f(mrun - mnew);
                mrun = mnew;
                float ls = 0.f;
#pragma unroll
                for (int rr = 0; rr < 16; ++rr) {
                    float p0 = __builtin_amdgcn_exp2f(s0[rr] - mnew);
                    float p1 = __builtin_amdgcn_exp2f(s1[rr] - mnew);
                    s0[rr] = p0; s1[rr] = p1;
                    ls += p0 + p1;
                }
                ls += __shfl_xor(ls, 32, 64);
                lrun = lrun * scl + ls;
#pragma unroll
                for (int rr = 0; rr < 16; ++rr) { oacc0[rr] *= scl; oacc1[rr] *= scl; }

                // P repack to B-frags entirely in registers:
                // per tile: 8 cvt_pk words, then swap(w0,w2),(w1,w3),(w4,w6),(w5,w7)
                unsigned int pw0[8], pw1[8];
#pragma unroll
                for (int k2 = 0; k2 < 8; ++k2) {
                    unsigned int wa, wb;
                    asm("v_cvt_pk_bf16_f32 %0, %1, %2" : "=v"(wa) : "v"(s0[2 * k2]), "v"(s0[2 * k2 + 1]));
                    asm("v_cvt_pk_bf16_f32 %0, %1, %2" : "=v"(wb) : "v"(s1[2 * k2]), "v"(s1[2 * k2 + 1]));
                    pw0[k2] = wa; pw1[k2] = wb;
                }
                asm("v_permlane32_swap_b32 %0, %1" : "+v"(pw0[0]), "+v"(pw0[2]));
                asm("v_permlane32_swap_b32 %0, %1" : "+v"(pw0[1]), "+v"(pw0[3]));
                asm("v_permlane32_swap_b32 %0, %1" : "+v"(pw0[4]), "+v"(pw0[6]));
                asm("v_permlane32_swap_b32 %0, %1" : "+v"(pw0[5]), "+v"(pw0[7]));
                asm("v_permlane32_swap_b32 %0, %1" : "+v"(pw1[0]), "+v"(pw1[2]));
                asm("v_permlane32_swap_b32 %0, %1" : "+v"(pw1[1]), "+v"(pw1[3]));
                asm("v_permlane32_swap_b32 %0, %1" : "+v"(pw1[4]), "+v"(pw1[6]));
                asm("v_permlane32_swap_b32 %0, %1" : "+v"(pw1[5]), "+v"(pw1[7]));
                union PU { unsigned int u[4]; short8 s8; };
                PU pb[4];
                pb[0].u[0] = pw0[0]; pb[0].u[1] = pw0[1]; pb[0].u[2] = pw0[2]; pb[0].u[3] = pw0[3];
                pb[1].u[0] = pw0[4]; pb[1].u[1] = pw0[5]; pb[1].u[2] = pw0[6]; pb[1].u[3] = pw0[7];
                pb[2].u[0] = pw1[0]; pb[2].u[1] = pw1[1]; pb[2].u[2] = pw1[2]; pb[2].u[3] = pw1[3];
                pb[3].u[0] = pw1[4]; pb[3].u[1] = pw1[5]; pb[3].u[2] = pw1[6]; pb[3].u[3] = pw1[7];

                // PV: O^T(d x i) += V^T-frags x P-frags
                __builtin_amdgcn_s_setprio(1);
#pragma unroll
                for (int c = 0; c < 4; ++c) {
                    int pc = ((2 * c + hl) ^ swz) * 8;
                    short8 va0 = *(const short8*)(sVp + i31 * 64 + pc);
                    short8 va1 = *(const short8*)(sVp + (32 + i31) * 64 + pc);
                    oacc0 = MFMA32(va0, pb[c].s8, oacc0);
                    oacc1 = MFMA32(va1, pb[c].s8, oacc1);
                }
                __builtin_amdgcn_s_setprio(0);
            }
            __syncthreads();
        }

        // merge odd-half into even-half via LDS, then epilogue by waves 0,1
        if (kvpar == 1) {
#pragma unroll
            for (int rr = 0; rr < 16; ++rr) {
                sMrgO[rb][l][rr]      = oacc0[rr];
                sMrgO[rb][l][16 + rr] = oacc1[rr];
            }
            sMrgS[rb][l][0] = mrun;
            sMrgS[rb][l][1] = lrun;
        }
        __syncthreads();
        if (kvpar == 0) {
            float mB = sMrgS[rb][l][0], lB = sMrgS[rb][l][1];
            float ms = fmaxf(mrun, mB);
            float sA = __builtin_amdgcn_exp2f(mrun - ms);
            float sB2 = __builtin_amdgcn_exp2f(mB - ms);
            float lt = lrun * sA + lB * sB2;
            float rinv = (lt > 0.f) ? 1.0f / lt : 0.f;
            // O^T: lane holds d = 32*td + 8*qd + 4*hl + (rr&3), col i = qrow
#pragma unroll
            for (int td = 0; td < 2; ++td)
#pragma unroll
                for (int qd = 0; qd < 4; ++qd) {
                    ushort4_t o4;
#pragma unroll
                    for (int e = 0; e < 4; ++e) {
                        float mine = td ? oacc1[qd * 4 + e] : oacc0[qd * 4 + e];
                        float ov = (mine * sA + sMrgO[rb][l][td * 16 + qd * 4 + e] * sB2) * rinv;
                        o4[e] = f2bf(ov);
                    }
                    *(ushort4_t*)(o_bf + (size_t)(bb * T_ + qrow) * D_
                                  + h * 64 + 32 * td + 8 * qd + 4 * hl) = o4;
                }
        }
        __syncthreads();
    }
}

// ---------------------------------------------------------------------------
extern "C" void kernel_launch(void* const* d_in, const int* in_sizes, int n_in,
                              void* d_out, int out_size, void* d_ws, size_t ws_size,
                              hipStream_t stream)
{
    const float* x     = (const float*)d_in[0];
    const float* m     = (const float*)d_in[1];
    const float* w_qkv = (const float*)d_in[2];
    const float* w_out = (const float*)d_in[3];
    const float* b_out = (const float*)d_in[4];
    float* out = (float*)d_out;

    char* ws = (char*)d_ws;
    unsigned short* x_bf   = (unsigned short*)(ws);                 // 8 MB
    unsigned short* wqkvT  = (unsigned short*)(ws + 8388608);       // 1.5 MB
    unsigned short* woutT  = (unsigned short*)(ws + 9961472);       // 0.5 MB
    unsigned short* qkv_bf = (unsigned short*)(ws + 10485760);      // 24 MB
    unsigned short* o_bf   = (unsigned short*)(ws + 35651584);      // 8 MB
    unsigned short* vT     = (unsigned short*)d_out;                // [32][64][2048] bf16 (dead until gemm_out)

    hipLaunchKernelGGL(prep_kernel, dim3(6144), dim3(256), 0, stream,
                       x, w_qkv, w_out, x_bf, wqkvT, woutT);
    hipLaunchKernelGGL(gemm_qkv_kernel, dim3(12, 64), dim3(256), 0, stream,
                       x_bf, wqkvT, qkv_bf, vT);
    hipLaunchKernelGGL(attn_kernel, dim3(16, 32), dim3(256), 0, stream,
                       qkv_bf, vT, m, o_bf);
    hipLaunchKernelGGL(gemm_out_kernel, dim3(4, 64), dim3(256), 0, stream,
                       o_bf, woutT, b_out, m, out);
}

// Round 5
// 99.647 us; speedup vs baseline: 1.9176x; 1.1280x over previous
//
#include <hip/hip_runtime.h>
#include <hip/hip_bf16.h>
#include <stdint.h>

#define B_ 4
#define T_ 2048
#define D_ 512
#define H_ 8
#define DH_ 64
#define M_TOT (B_*T_)     // 8192
#define N_QKV (3*D_)      // 1536
// 0.125 * log2(e): folds softmax scale and exp->exp2 conversion into Q
#define QSCALE_ 0.18033688011112043f
#define NEGINF_ -3.0e38f

typedef __attribute__((ext_vector_type(8))) short short8;
typedef __attribute__((ext_vector_type(8))) unsigned short ushort8;
typedef __attribute__((ext_vector_type(4))) unsigned short ushort4_t;
typedef __attribute__((ext_vector_type(4))) float f32x4;
typedef __attribute__((ext_vector_type(16))) float f32x16;

#define MFMA32(a,b,c) __builtin_amdgcn_mfma_f32_32x32x16_bf16(a,b,c,0,0,0)
#define MFMA16(a,b,c) __builtin_amdgcn_mfma_f32_16x16x32_bf16(a,b,c,0,0,0)

static __device__ __forceinline__ unsigned short f2bf(float f) {
    union { float f; unsigned u; } v; v.f = f;
    unsigned r = v.u + 0x7fffu + ((v.u >> 16) & 1u);
    return (unsigned short)(r >> 16);
}

// ---------------------------------------------------------------------------
// prep: x -> bf16; w_qkv, w_out -> bf16 transposed [N][K]; per-tile pad flags
// ---------------------------------------------------------------------------
__global__ __launch_bounds__(256) void prep_kernel(
    const float* __restrict__ x, const float* __restrict__ w_qkv,
    const float* __restrict__ w_out, const float* __restrict__ m,
    unsigned short* __restrict__ x_bf, unsigned short* __restrict__ wqkvT,
    unsigned short* __restrict__ woutT, int* __restrict__ padflags)
{
    const int NX  = M_TOT * D_ / 8;
    const int NW1 = D_ * N_QKV;
    const int NW2 = D_ * D_;
    int tid = blockIdx.x * 256 + threadIdx.x;
    if (tid < NX) {
        int i = tid * 8;
        f32x4 a = *(const f32x4*)(x + i);
        f32x4 b = *(const f32x4*)(x + i + 4);
        ushort8 o;
        o[0] = f2bf(a[0]); o[1] = f2bf(a[1]); o[2] = f2bf(a[2]); o[3] = f2bf(a[3]);
        o[4] = f2bf(b[0]); o[5] = f2bf(b[1]); o[6] = f2bf(b[2]); o[7] = f2bf(b[3]);
        *(ushort8*)(x_bf + i) = o;
    } else if (tid < NX + NW1) {
        int idx = tid - NX;
        int k = idx & 511, n = idx >> 9;
        wqkvT[n * 512 + k] = f2bf(w_qkv[k * N_QKV + n]);
    } else if (tid < NX + NW1 + NW2) {
        int idx = tid - NX - NW1;
        int k = idx & 511, n = idx >> 9;
        woutT[n * 512 + k] = f2bf(w_out[k * D_ + n]);
    } else if (tid < NX + NW1 + NW2 + 128) {
        int idx = tid - NX - NW1 - NW2;
        int b = idx >> 5, jt = idx & 31;
        const float* mp = m + b * T_ + jt * 64;
        int any = 0;
#pragma unroll 8
        for (int t = 0; t < 64; ++t) any |= (mp[t] == 0.f) ? 1 : 0;
        padflags[idx] = any;
    }
}

// ---------------------------------------------------------------------------
// GEMM body: C[128][128] tile, BK=64, global_load_lds(16) staging into linear
// LDS with inverse-swizzled global source (chunk c = p ^ (r&7)); frag reads
// apply the same XOR -> all 32 banks covered (BW floor).
// ---------------------------------------------------------------------------
__device__ __forceinline__ void gemm_tile_128(
    const unsigned short* __restrict__ A, const unsigned short* __restrict__ Bt,
    int bm, int bn, unsigned short* sA, unsigned short* sB, f32x4 acc[4][4])
{
    const int tid = threadIdx.x;
    const int w = tid >> 6, l = tid & 63;
    const int wr = (w >> 1) * 64, wc = (w & 1) * 64;
    const int lr = l >> 3, lp = l & 7;     // staging: row-in-group, chunk pos
    const int i16 = l & 15, g = l >> 4;    // frag: row, k-group
#pragma unroll
    for (int mi = 0; mi < 4; ++mi)
#pragma unroll
        for (int ni = 0; ni < 4; ++ni)
#pragma unroll
            for (int r = 0; r < 4; ++r) acc[mi][ni][r] = 0.f;

    for (int kt = 0; kt < 512; kt += 64) {
#pragma unroll
        for (int i = 0; i < 4; ++i) {
            int r = w * 32 + i * 8 + lr;
            int c = lp ^ (r & 7);
            __builtin_amdgcn_global_load_lds(
                (const __attribute__((address_space(1))) void*)(A + (size_t)(bm + r) * 512 + kt + c * 8),
                (__attribute__((address_space(3))) void*)(sA + (w * 32 + i * 8) * 64),
                16, 0, 0);
            __builtin_amdgcn_global_load_lds(
                (const __attribute__((address_space(1))) void*)(Bt + (size_t)(bn + r) * 512 + kt + c * 8),
                (__attribute__((address_space(3))) void*)(sB + (w * 32 + i * 8) * 64),
                16, 0, 0);
        }
        __syncthreads();   // drains vmcnt before frag reads
#pragma unroll
        for (int kk = 0; kk < 2; ++kk) {
            short8 af[4], bf2[4];
#pragma unroll
            for (int i = 0; i < 4; ++i) {
                int ra = wr + i * 16 + i16;
                af[i]  = *(const short8*)(sA + ra * 64 + (((kk * 4 + g) ^ (ra & 7)) * 8));
                int rb = wc + i * 16 + i16;
                bf2[i] = *(const short8*)(sB + rb * 64 + (((kk * 4 + g) ^ (rb & 7)) * 8));
            }
#pragma unroll
            for (int mi = 0; mi < 4; ++mi)
#pragma unroll
                for (int ni = 0; ni < 4; ++ni)
                    acc[mi][ni] = MFMA16(af[mi], bf2[ni], acc[mi][ni]);
        }
        __syncthreads();
    }
}

__global__ __launch_bounds__(256) void gemm_qkv_kernel(
    const unsigned short* __restrict__ A, const unsigned short* __restrict__ Bt,
    unsigned short* __restrict__ qkv, unsigned short* __restrict__ vT)
{
    __shared__ __align__(16) unsigned short sA[128 * 64];
    __shared__ __align__(16) unsigned short sB[128 * 64];
    f32x4 acc[4][4];
    int bn = blockIdx.x * 128, bm = blockIdx.y * 128;
    gemm_tile_128(A, Bt, bm, bn, sA, sB, acc);
    const int l = threadIdx.x & 63, w = threadIdx.x >> 6;
    const int wr = (w >> 1) * 64, wc = (w & 1) * 64;
    if (bn < 1024) {
        bool isQ = (bn < 512);
#pragma unroll
        for (int mi = 0; mi < 4; ++mi)
#pragma unroll
            for (int ni = 0; ni < 4; ++ni)
#pragma unroll
                for (int r = 0; r < 4; ++r) {
                    int row = bm + wr + mi * 16 + (l >> 4) * 4 + r;
                    int col = bn + wc + ni * 16 + (l & 15);
                    float v = acc[mi][ni][r];
                    if (isQ) v *= QSCALE_;
                    qkv[(size_t)row * N_QKV + col] = f2bf(v);
                }
    } else {
#pragma unroll
        for (int mi = 0; mi < 4; ++mi)
#pragma unroll
            for (int ni = 0; ni < 4; ++ni) {
                int row0 = bm + wr + mi * 16 + (l >> 4) * 4;
                int dall = bn - 1024 + wc + ni * 16 + (l & 15);
                int hh = dall >> 6, d = dall & 63;
                int b = row0 >> 11, t0 = row0 & 2047;
                ushort4_t vv;
#pragma unroll
                for (int r = 0; r < 4; ++r) vv[r] = f2bf(acc[mi][ni][r]);
                *(ushort4_t*)(vT + ((size_t)((b * 8 + hh) * 64 + d)) * T_ + t0) = vv;
            }
    }
}

__global__ __launch_bounds__(256) void gemm_out_kernel(
    const unsigned short* __restrict__ A, const unsigned short* __restrict__ Bt,
    const float* __restrict__ b_out, const float* __restrict__ m,
    float* __restrict__ out)
{
    __shared__ __align__(16) unsigned short sA[128 * 64];
    __shared__ __align__(16) unsigned short sB[128 * 64];
    f32x4 acc[4][4];
    int bn = blockIdx.x * 128, bm = blockIdx.y * 128;
    gemm_tile_128(A, Bt, bm, bn, sA, sB, acc);
    const int l = threadIdx.x & 63, w = threadIdx.x >> 6;
    const int wr = (w >> 1) * 64, wc = (w & 1) * 64;
#pragma unroll
    for (int mi = 0; mi < 4; ++mi)
#pragma unroll
        for (int ni = 0; ni < 4; ++ni)
#pragma unroll
            for (int r = 0; r < 4; ++r) {
                int row = bm + wr + mi * 16 + (l >> 4) * 4 + r;
                int col = bn + wc + ni * 16 + (l & 15);
                out[(size_t)row * D_ + col] = (acc[mi][ni][r] + b_out[col]) * m[row];
            }
}

// ---------------------------------------------------------------------------
// Flash attention. Grid (bh=32, 32): x = bh (same-bh blocks share an XCD's L2
// via id%8 congruence), y -> q = 31-y (LPT: longest blocks first). One Q-tile
// of 64 rows per block; waves 0,1 = rows 0-31/32-63 on even KV tiles, waves
// 2,3 same rows on odd tiles; merge via LDS (aliased over K/V buffers).
// 32x32 MFMA, in-register P repack (cvt_pk + permlane32_swap), defer-max,
// pad-skip via precomputed flags.
// ---------------------------------------------------------------------------
__global__ __launch_bounds__(256) void attn_kernel(
    const unsigned short* __restrict__ qkv, const unsigned short* __restrict__ vT,
    const float* __restrict__ m, const int* __restrict__ padflags,
    unsigned short* __restrict__ o_bf)
{
    __shared__ __align__(16) char smem[33280];
    unsigned short* sK0 = (unsigned short*)smem;            // [64][64] swizzled
    unsigned short* sK1 = (unsigned short*)(smem + 8192);
    unsigned short* sV0 = (unsigned short*)(smem + 16384);
    unsigned short* sV1 = (unsigned short*)(smem + 24576);
    float* sBias = (float*)(smem + 32768);                  // [2][64]
    float* sMrgO = (float*)smem;                            // [2][64][33] (aliased, post-loop)
    float* sMrgS = (float*)(smem + 16896);                  // [2][64][2]

    const int tid = threadIdx.x, wv = tid >> 6, l = tid & 63;
    const int i31 = l & 31, hl = l >> 5;
    const int kvpar = wv >> 1;             // 0: even KV tiles, 1: odd
    const int rb = wv & 1;                 // 0: q-rows 0-31, 1: 32-63
    const int bh = blockIdx.x, bb = bh >> 3, h = bh & 7;
    const int q = 31 - (int)blockIdx.y;    // LPT order
    const int qb = q * 64;
    const int qrow = qb + rb * 32 + i31;
    const int swz = i31 & 7;

    short8 bq[4];
#pragma unroll
    for (int c = 0; c < 4; ++c)
        bq[c] = *(const short8*)(qkv + (size_t)(bb * T_ + qrow) * N_QKV
                                 + h * 64 + c * 16 + hl * 8);

    f32x16 oacc0, oacc1;
#pragma unroll
    for (int rr = 0; rr < 16; ++rr) { oacc0[rr] = 0.f; oacc1[rr] = 0.f; }
    float mrun = -1e30f, lrun = 0.f;

    const int nss = (q >> 1) + 1;
#pragma unroll 1
    for (int ss = 0; ss < nss; ++ss) {
        const int jtA = 2 * ss, jtB = 2 * ss + 1;
        const bool hasB = (jtB <= q);
        const int pfA = padflags[bb * 32 + jtA];
        const int pfB = hasB ? padflags[bb * 32 + jtB] : 0;
        {   // stage K rows + V^T rows, XOR-swizzled chunk positions
            int row = tid >> 2;
            int c2 = (tid & 3) * 2, cg16 = (tid & 3) * 16;
            int cc0 = ((c2) ^ (row & 7)) * 8;
            int cc1 = ((c2 + 1) ^ (row & 7)) * 8;
            const unsigned short* kgA = qkv + (size_t)(bb * T_ + jtA * 64 + row) * N_QKV + 512 + h * 64 + cg16;
            *(ushort8*)(sK0 + row * 64 + cc0) = *(const ushort8*)kgA;
            *(ushort8*)(sK0 + row * 64 + cc1) = *(const ushort8*)(kgA + 8);
            const unsigned short* vgA = vT + (size_t)(bh * 64 + row) * T_ + jtA * 64 + cg16;
            *(ushort8*)(sV0 + row * 64 + cc0) = *(const ushort8*)vgA;
            *(ushort8*)(sV0 + row * 64 + cc1) = *(const ushort8*)(vgA + 8);
            if (hasB) {
                const unsigned short* kgB = qkv + (size_t)(bb * T_ + jtB * 64 + row) * N_QKV + 512 + h * 64 + cg16;
                *(ushort8*)(sK1 + row * 64 + cc0) = *(const ushort8*)kgB;
                *(ushort8*)(sK1 + row * 64 + cc1) = *(const ushort8*)(kgB + 8);
                const unsigned short* vgB = vT + (size_t)(bh * 64 + row) * T_ + jtB * 64 + cg16;
                *(ushort8*)(sV1 + row * 64 + cc0) = *(const ushort8*)vgB;
                *(ushort8*)(sV1 + row * 64 + cc1) = *(const ushort8*)(vgB + 8);
            }
            if (tid < 128) {
                int tI = tid >> 6, jl = tid & 63;
                int pf = tI ? pfB : pfA;
                if (pf) {
                    int jt = tI ? jtB : jtA;
                    sBias[tI * 64 + jl] = (m[bb * T_ + jt * 64 + jl] != 0.f) ? 0.f : NEGINF_;
                }
            }
        }
        __syncthreads();

        const int jt = kvpar ? jtB : jtA;
        const int pf = kvpar ? pfB : pfA;
        if (kvpar == 0 || hasB) {
            const int j0 = jt * 64;
            const unsigned short* sKp = kvpar ? sK1 : sK0;
            const unsigned short* sVp = kvpar ? sV1 : sV0;

            // S^T = K Q^T: two 32x32 C-tiles (j 0-31, 32-63)
            f32x16 s0, s1;
#pragma unroll
            for (int rr = 0; rr < 16; ++rr) { s0[rr] = 0.f; s1[rr] = 0.f; }
            __builtin_amdgcn_s_setprio(1);
#pragma unroll
            for (int c = 0; c < 4; ++c) {
                int pc = ((2 * c + hl) ^ swz) * 8;
                short8 ka0 = *(const short8*)(sKp + i31 * 64 + pc);
                short8 ka1 = *(const short8*)(sKp + (32 + i31) * 64 + pc);
                s0 = MFMA32(ka0, bq[c], s0);
                s1 = MFMA32(ka1, bq[c], s1);
            }
            __builtin_amdgcn_s_setprio(0);

            // masks: causal only on diagonal tile; pad bias only if flagged
            if (jt == q) {
#pragma unroll
                for (int qd = 0; qd < 4; ++qd)
#pragma unroll
                    for (int e = 0; e < 4; ++e) {
                        int jl0 = 8 * qd + 4 * hl + e;
                        if (j0 + jl0 > qrow)      s0[qd * 4 + e] = NEGINF_;
                        if (j0 + 32 + jl0 > qrow) s1[qd * 4 + e] = NEGINF_;
                    }
            }
            if (pf) {
#pragma unroll
                for (int qd = 0; qd < 4; ++qd) {
                    f32x4 b0 = *(const f32x4*)(&sBias[kvpar * 64 + 8 * qd + 4 * hl]);
                    f32x4 b1 = *(const f32x4*)(&sBias[kvpar * 64 + 32 + 8 * qd + 4 * hl]);
#pragma unroll
                    for (int e = 0; e < 4; ++e) {
                        s0[qd * 4 + e] += b0[e];
                        s1[qd * 4 + e] += b1[e];
                    }
                }
            }

            // online softmax with defer-max (T13): lane owns q-row qrow
            float pm = NEGINF_;
#pragma unroll
            for (int rr = 0; rr < 16; ++rr)
                pm = fmaxf(pm, fmaxf(s0[rr], s1[rr]));
            pm = fmaxf(pm, __shfl_xor(pm, 32, 64));
            if (__all(pm - mrun <= 8.f)) {
                // deferred: no rescale, keep mrun
                float ls = 0.f;
#pragma unroll
                for (int rr = 0; rr < 16; ++rr) {
                    float p0 = __builtin_amdgcn_exp2f(s0[rr] - mrun);
                    float p1 = __builtin_amdgcn_exp2f(s1[rr] - mrun);
                    s0[rr] = p0; s1[rr] = p1;
                    ls += p0 + p1;
                }
                ls += __shfl_xor(ls, 32, 64);
                lrun += ls;
            } else {
                float mnew = fmaxf(mrun, pm);
                float scl = __builtin_amdgcn_exp2f(mrun - mnew);
                mrun = mnew;
                float ls = 0.f;
#pragma unroll
                for (int rr = 0; rr < 16; ++rr) {
                    float p0 = __builtin_amdgcn_exp2f(s0[rr] - mnew);
                    float p1 = __builtin_amdgcn_exp2f(s1[rr] - mnew);
                    s0[rr] = p0; s1[rr] = p1;
                    ls += p0 + p1;
                }
                ls += __shfl_xor(ls, 32, 64);
                lrun = lrun * scl + ls;
#pragma unroll
                for (int rr = 0; rr < 16; ++rr) { oacc0[rr] *= scl; oacc1[rr] *= scl; }
            }

            // P repack to B-frags in registers: cvt_pk pairs + permlane32_swap
            unsigned int pw0[8], pw1[8];
#pragma unroll
            for (int k2 = 0; k2 < 8; ++k2) {
                unsigned int wa, wb;
                asm("v_cvt_pk_bf16_f32 %0, %1, %2" : "=v"(wa) : "v"(s0[2 * k2]), "v"(s0[2 * k2 + 1]));
                asm("v_cvt_pk_bf16_f32 %0, %1, %2" : "=v"(wb) : "v"(s1[2 * k2]), "v"(s1[2 * k2 + 1]));
                pw0[k2] = wa; pw1[k2] = wb;
            }
            asm("v_permlane32_swap_b32 %0, %1" : "+v"(pw0[0]), "+v"(pw0[2]));
            asm("v_permlane32_swap_b32 %0, %1" : "+v"(pw0[1]), "+v"(pw0[3]));
            asm("v_permlane32_swap_b32 %0, %1" : "+v"(pw0[4]), "+v"(pw0[6]));
            asm("v_permlane32_swap_b32 %0, %1" : "+v"(pw0[5]), "+v"(pw0[7]));
            asm("v_permlane32_swap_b32 %0, %1" : "+v"(pw1[0]), "+v"(pw1[2]));
            asm("v_permlane32_swap_b32 %0, %1" : "+v"(pw1[1]), "+v"(pw1[3]));
            asm("v_permlane32_swap_b32 %0, %1" : "+v"(pw1[4]), "+v"(pw1[6]));
            asm("v_permlane32_swap_b32 %0, %1" : "+v"(pw1[5]), "+v"(pw1[7]));
            union PU { unsigned int u[4]; short8 s8; };
            PU pb[4];
            pb[0].u[0] = pw0[0]; pb[0].u[1] = pw0[1]; pb[0].u[2] = pw0[2]; pb[0].u[3] = pw0[3];
            pb[1].u[0] = pw0[4]; pb[1].u[1] = pw0[5]; pb[1].u[2] = pw0[6]; pb[1].u[3] = pw0[7];
            pb[2].u[0] = pw1[0]; pb[2].u[1] = pw1[1]; pb[2].u[2] = pw1[2]; pb[2].u[3] = pw1[3];
            pb[3].u[0] = pw1[4]; pb[3].u[1] = pw1[5]; pb[3].u[2] = pw1[6]; pb[3].u[3] = pw1[7];

            // PV: O^T(d x i) += V^T-frags x P-frags
            __builtin_amdgcn_s_setprio(1);
#pragma unroll
            for (int c = 0; c < 4; ++c) {
                int pc = ((2 * c + hl) ^ swz) * 8;
                short8 va0 = *(const short8*)(sVp + i31 * 64 + pc);
                short8 va1 = *(const short8*)(sVp + (32 + i31) * 64 + pc);
                oacc0 = MFMA32(va0, pb[c].s8, oacc0);
                oacc1 = MFMA32(va1, pb[c].s8, oacc1);
            }
            __builtin_amdgcn_s_setprio(0);
        }
        __syncthreads();
    }

    // merge odd-half into even-half via LDS (aliased region), then epilogue
    if (kvpar == 1) {
#pragma unroll
        for (int rr = 0; rr < 16; ++rr) {
            sMrgO[(rb * 64 + l) * 33 + rr]      = oacc0[rr];
            sMrgO[(rb * 64 + l) * 33 + 16 + rr] = oacc1[rr];
        }
        sMrgS[(rb * 64 + l) * 2 + 0] = mrun;
        sMrgS[(rb * 64 + l) * 2 + 1] = lrun;
    }
    __syncthreads();
    if (kvpar == 0) {
        float mB = sMrgS[(rb * 64 + l) * 2 + 0], lB = sMrgS[(rb * 64 + l) * 2 + 1];
        float ms = fmaxf(mrun, mB);
        float sA2 = __builtin_amdgcn_exp2f(mrun - ms);
        float sB2 = __builtin_amdgcn_exp2f(mB - ms);
        float lt = lrun * sA2 + lB * sB2;
        float rinv = (lt > 0.f) ? 1.0f / lt : 0.f;
#pragma unroll
        for (int td = 0; td < 2; ++td)
#pragma unroll
            for (int qd = 0; qd < 4; ++qd) {
                ushort4_t o4;
#pragma unroll
                for (int e = 0; e < 4; ++e) {
                    float mine = td ? oacc1[qd * 4 + e] : oacc0[qd * 4 + e];
                    float ov = (mine * sA2 + sMrgO[(rb * 64 + l) * 33 + td * 16 + qd * 4 + e] * sB2) * rinv;
                    o4[e] = f2bf(ov);
                }
                *(ushort4_t*)(o_bf + (size_t)(bb * T_ + qrow) * D_
                              + h * 64 + 32 * td + 8 * qd + 4 * hl) = o4;
            }
    }
}

// ---------------------------------------------------------------------------
extern "C" void kernel_launch(void* const* d_in, const int* in_sizes, int n_in,
                              void* d_out, int out_size, void* d_ws, size_t ws_size,
                              hipStream_t stream)
{
    const float* x     = (const float*)d_in[0];
    const float* m     = (const float*)d_in[1];
    const float* w_qkv = (const float*)d_in[2];
    const float* w_out = (const float*)d_in[3];
    const float* b_out = (const float*)d_in[4];
    float* out = (float*)d_out;

    char* ws = (char*)d_ws;
    unsigned short* x_bf   = (unsigned short*)(ws);                 // 8 MB
    unsigned short* wqkvT  = (unsigned short*)(ws + 8388608);       // 1.5 MB
    unsigned short* woutT  = (unsigned short*)(ws + 9961472);       // 0.5 MB
    unsigned short* qkv_bf = (unsigned short*)(ws + 10485760);      // 24 MB
    unsigned short* o_bf   = (unsigned short*)(ws + 35651584);      // 8 MB
    // d_out (16 MB) is dead until gemm_out: stash vT in [0,8MB), padflags after it
    unsigned short* vT     = (unsigned short*)d_out;                // [32][64][2048] bf16
    int* padflags          = (int*)((char*)d_out + 8388608);        // 128 ints

    hipLaunchKernelGGL(prep_kernel, dim3(6145), dim3(256), 0, stream,
                       x, w_qkv, w_out, m, x_bf, wqkvT, woutT, padflags);
    hipLaunchKernelGGL(gemm_qkv_kernel, dim3(12, 64), dim3(256), 0, stream,
                       x_bf, wqkvT, qkv_bf, vT);
    hipLaunchKernelGGL(attn_kernel, dim3(32, 32), dim3(256), 0, stream,
                       qkv_bf, vT, m, padflags, o_bf);
    hipLaunchKernelGGL(gemm_out_kernel, dim3(4, 64), dim3(256), 0, stream,
                       o_bf, woutT, b_out, m, out);
}

// Round 8
// 95.794 us; speedup vs baseline: 1.9948x; 1.0402x over previous
//
#include <hip/hip_runtime.h>
#include <hip/hip_bf16.h>
#include <stdint.h>

#define B_ 4
#define T_ 2048
#define D_ 512
#define H_ 8
#define DH_ 64
#define M_TOT (B_*T_)     // 8192
#define N_QKV (3*D_)      // 1536
// 0.125 * log2(e): folds softmax scale and exp->exp2 conversion into Q
#define QSCALE_ 0.18033688011112043f
#define NEGINF_ -3.0e38f

typedef __attribute__((ext_vector_type(8))) short short8;
typedef __attribute__((ext_vector_type(8))) unsigned short ushort8;
typedef __attribute__((ext_vector_type(4))) unsigned short ushort4_t;
typedef __attribute__((ext_vector_type(4))) float f32x4;
typedef __attribute__((ext_vector_type(16))) float f32x16;

#define MFMA32(a,b,c) __builtin_amdgcn_mfma_f32_32x32x16_bf16(a,b,c,0,0,0)
#define MFMA16(a,b,c) __builtin_amdgcn_mfma_f32_16x16x32_bf16(a,b,c,0,0,0)

static __device__ __forceinline__ unsigned short f2bf(float f) {
    union { float f; unsigned u; } v; v.f = f;
    unsigned r = v.u + 0x7fffu + ((v.u >> 16) & 1u);
    return (unsigned short)(r >> 16);
}

// ---------------------------------------------------------------------------
// prep: x -> bf16; w_qkv, w_out -> bf16 transposed [N][K]; per-tile pad flags
// ---------------------------------------------------------------------------
__global__ __launch_bounds__(256) void prep_kernel(
    const float* __restrict__ x, const float* __restrict__ w_qkv,
    const float* __restrict__ w_out, const float* __restrict__ m,
    unsigned short* __restrict__ x_bf, unsigned short* __restrict__ wqkvT,
    unsigned short* __restrict__ woutT, int* __restrict__ padflags)
{
    const int NX  = M_TOT * D_ / 8;
    const int NW1 = D_ * N_QKV;
    const int NW2 = D_ * D_;
    int tid = blockIdx.x * 256 + threadIdx.x;
    if (tid < NX) {
        int i = tid * 8;
        f32x4 a = *(const f32x4*)(x + i);
        f32x4 b = *(const f32x4*)(x + i + 4);
        ushort8 o;
        o[0] = f2bf(a[0]); o[1] = f2bf(a[1]); o[2] = f2bf(a[2]); o[3] = f2bf(a[3]);
        o[4] = f2bf(b[0]); o[5] = f2bf(b[1]); o[6] = f2bf(b[2]); o[7] = f2bf(b[3]);
        *(ushort8*)(x_bf + i) = o;
    } else if (tid < NX + NW1) {
        int idx = tid - NX;
        int k = idx & 511, n = idx >> 9;
        wqkvT[n * 512 + k] = f2bf(w_qkv[k * N_QKV + n]);
    } else if (tid < NX + NW1 + NW2) {
        int idx = tid - NX - NW1;
        int k = idx & 511, n = idx >> 9;
        woutT[n * 512 + k] = f2bf(w_out[k * D_ + n]);
    } else if (tid < NX + NW1 + NW2 + 128) {
        int idx = tid - NX - NW1 - NW2;
        int b = idx >> 5, jt = idx & 31;
        const float* mp = m + b * T_ + jt * 64;
        int any = 0;
#pragma unroll 8
        for (int t = 0; t < 64; ++t) any |= (mp[t] == 0.f) ? 1 : 0;
        padflags[idx] = any;
    }
}

// ---------------------------------------------------------------------------
// GEMM body: BK=64, global_load_lds(16), XOR swizzle (unchanged, proven)
// ---------------------------------------------------------------------------
__device__ __forceinline__ void gemm_tile_128(
    const unsigned short* __restrict__ A, const unsigned short* __restrict__ Bt,
    int bm, int bn, unsigned short* sA, unsigned short* sB, f32x4 acc[4][4])
{
    const int tid = threadIdx.x;
    const int w = tid >> 6, l = tid & 63;
    const int wr = (w >> 1) * 64, wc = (w & 1) * 64;
    const int lr = l >> 3, lp = l & 7;
    const int i16 = l & 15, g = l >> 4;
#pragma unroll
    for (int mi = 0; mi < 4; ++mi)
#pragma unroll
        for (int ni = 0; ni < 4; ++ni)
#pragma unroll
            for (int r = 0; r < 4; ++r) acc[mi][ni][r] = 0.f;

    for (int kt = 0; kt < 512; kt += 64) {
#pragma unroll
        for (int i = 0; i < 4; ++i) {
            int r = w * 32 + i * 8 + lr;
            int c = lp ^ (r & 7);
            __builtin_amdgcn_global_load_lds(
                (const __attribute__((address_space(1))) void*)(A + (size_t)(bm + r) * 512 + kt + c * 8),
                (__attribute__((address_space(3))) void*)(sA + (w * 32 + i * 8) * 64),
                16, 0, 0);
            __builtin_amdgcn_global_load_lds(
                (const __attribute__((address_space(1))) void*)(Bt + (size_t)(bn + r) * 512 + kt + c * 8),
                (__attribute__((address_space(3))) void*)(sB + (w * 32 + i * 8) * 64),
                16, 0, 0);
        }
        __syncthreads();
#pragma unroll
        for (int kk = 0; kk < 2; ++kk) {
            short8 af[4], bf2[4];
#pragma unroll
            for (int i = 0; i < 4; ++i) {
                int ra = wr + i * 16 + i16;
                af[i]  = *(const short8*)(sA + ra * 64 + (((kk * 4 + g) ^ (ra & 7)) * 8));
                int rb = wc + i * 16 + i16;
                bf2[i] = *(const short8*)(sB + rb * 64 + (((kk * 4 + g) ^ (rb & 7)) * 8));
            }
#pragma unroll
            for (int mi = 0; mi < 4; ++mi)
#pragma unroll
                for (int ni = 0; ni < 4; ++ni)
                    acc[mi][ni] = MFMA16(af[mi], bf2[ni], acc[mi][ni]);
        }
        __syncthreads();
    }
}

__global__ __launch_bounds__(256) void gemm_qkv_kernel(
    const unsigned short* __restrict__ A, const unsigned short* __restrict__ Bt,
    unsigned short* __restrict__ qkv, unsigned short* __restrict__ vT)
{
    __shared__ __align__(16) unsigned short sA[128 * 64];
    __shared__ __align__(16) unsigned short sB[128 * 64];
    f32x4 acc[4][4];
    int bn = blockIdx.x * 128, bm = blockIdx.y * 128;
    gemm_tile_128(A, Bt, bm, bn, sA, sB, acc);
    const int l = threadIdx.x & 63, w = threadIdx.x >> 6;
    const int wr = (w >> 1) * 64, wc = (w & 1) * 64;
    if (bn < 1024) {
        bool isQ = (bn < 512);
#pragma unroll
        for (int mi = 0; mi < 4; ++mi)
#pragma unroll
            for (int ni = 0; ni < 4; ++ni)
#pragma unroll
                for (int r = 0; r < 4; ++r) {
                    int row = bm + wr + mi * 16 + (l >> 4) * 4 + r;
                    int col = bn + wc + ni * 16 + (l & 15);
                    float v = acc[mi][ni][r];
                    if (isQ) v *= QSCALE_;
                    qkv[(size_t)row * N_QKV + col] = f2bf(v);
                }
    } else {
#pragma unroll
        for (int mi = 0; mi < 4; ++mi)
#pragma unroll
            for (int ni = 0; ni < 4; ++ni) {
                int row0 = bm + wr + mi * 16 + (l >> 4) * 4;
                int dall = bn - 1024 + wc + ni * 16 + (l & 15);
                int hh = dall >> 6, d = dall & 63;
                int b = row0 >> 11, t0 = row0 & 2047;
                ushort4_t vv;
#pragma unroll
                for (int r = 0; r < 4; ++r) vv[r] = f2bf(acc[mi][ni][r]);
                *(ushort4_t*)(vT + ((size_t)((b * 8 + hh) * 64 + d)) * T_ + t0) = vv;
            }
    }
}

__global__ __launch_bounds__(256) void gemm_out_kernel(
    const unsigned short* __restrict__ A, const unsigned short* __restrict__ Bt,
    const float* __restrict__ b_out, const float* __restrict__ m,
    float* __restrict__ out)
{
    __shared__ __align__(16) unsigned short sA[128 * 64];
    __shared__ __align__(16) unsigned short sB[128 * 64];
    f32x4 acc[4][4];
    int bn = blockIdx.x * 128, bm = blockIdx.y * 128;
    gemm_tile_128(A, Bt, bm, bn, sA, sB, acc);
    const int l = threadIdx.x & 63, w = threadIdx.x >> 6;
    const int wr = (w >> 1) * 64, wc = (w & 1) * 64;
#pragma unroll
    for (int mi = 0; mi < 4; ++mi)
#pragma unroll
        for (int ni = 0; ni < 4; ++ni)
#pragma unroll
            for (int r = 0; r < 4; ++r) {
                int row = bm + wr + mi * 16 + (l >> 4) * 4 + r;
                int col = bn + wc + ni * 16 + (l & 15);
                out[(size_t)row * D_ + col] = (acc[mi][ni][r] + b_out[col]) * m[row];
            }
}

// ---------------------------------------------------------------------------
// Flash attention — ROUND-5 STRUCTURE RESTORED (passed @52us), with ONE graft:
// K/V staging via per-wave global_load_lds (linear LDS dest, pre-swizzled
// per-lane global source; wave wv stages tile kvp_s=wv>>1, part kv_s=wv&1),
// + explicit vmcnt(0) before the stage barrier. Single-buffered, two barriers
// per superstep, grid (32,32) one Q-tile per block, q = 31 - blockIdx.y.
// Softmax: round-5 shfl-based pm/lrun + defer-max. P repack in registers.
// ---------------------------------------------------------------------------
__global__ __launch_bounds__(256) void attn_kernel(
    const unsigned short* __restrict__ qkv, const unsigned short* __restrict__ vT,
    const float* __restrict__ m, const int* __restrict__ padflags,
    unsigned short* __restrict__ o_bf)
{
    __shared__ __align__(16) char smem[33280];
    unsigned short* sK0 = (unsigned short*)smem;            // [64][64] swizzled
    unsigned short* sK1 = (unsigned short*)(smem + 8192);
    unsigned short* sV0 = (unsigned short*)(smem + 16384);
    unsigned short* sV1 = (unsigned short*)(smem + 24576);
    float* sBias = (float*)(smem + 32768);                  // [2][64]
    float* sMrgO = (float*)smem;                            // aliased post-loop
    float* sMrgS = (float*)(smem + 16896);

    const int tid = threadIdx.x, wv = tid >> 6, l = tid & 63;
    const int i31 = l & 31, hl = l >> 5;
    const int kvpar = wv >> 1;             // compute: even/odd KV tiles
    const int rb = wv & 1;                 // compute: q-rows 0-31 / 32-63
    const int bh = blockIdx.x, bb = bh >> 3, h = bh & 7;
    const int q = 31 - (int)blockIdx.y;    // LPT order
    const int qb = q * 64;
    const int qrow = qb + rb * 32 + i31;
    const int swz = i31 & 7;
    // staging role: wave wv stages tile kvp_s (even/odd), part kv_s (K/V)
    const int lr = l >> 3, lp = l & 7, cst = lp ^ lr;
    const int kv_s = wv & 1, kvp_s = wv >> 1;

    short8 bq[4];
#pragma unroll
    for (int c = 0; c < 4; ++c)
        bq[c] = *(const short8*)(qkv + (size_t)(bb * T_ + qrow) * N_QKV
                                 + h * 64 + c * 16 + hl * 8);

    f32x16 oacc0, oacc1;
#pragma unroll
    for (int rr = 0; rr < 16; ++rr) { oacc0[rr] = 0.f; oacc1[rr] = 0.f; }
    float mrun = -1e30f, lrun = 0.f;

    const int nss = (q >> 1) + 1;
#pragma unroll 1
    for (int ss = 0; ss < nss; ++ss) {
        const int jtA = 2 * ss, jtB = 2 * ss + 1;
        const bool hasB = (jtB <= q);
        const int pfA = padflags[bb * 32 + jtA];
        const int pfB = hasB ? padflags[bb * 32 + jtB] : 0;
        {   // stage via global_load_lds: wave wv -> tile kvp_s, part kv_s
            int jtn = 2 * ss + kvp_s;
            if (jtn <= q) {
                char* dst0 = smem + kv_s * 16384 + kvp_s * 8192;
                if (kv_s == 0) {
                    const unsigned short* src = qkv + (size_t)(bb * T_ + jtn * 64 + lr) * N_QKV
                                                + 512 + h * 64 + cst * 8;
#pragma unroll
                    for (int is = 0; is < 8; ++is)
                        __builtin_amdgcn_global_load_lds(
                            (const __attribute__((address_space(1))) void*)(src + (size_t)is * 8 * N_QKV),
                            (__attribute__((address_space(3))) void*)(dst0 + is * 1024), 16, 0, 0);
                } else {
                    const unsigned short* src = vT + (size_t)(bh * 64 + lr) * T_
                                                + jtn * 64 + cst * 8;
#pragma unroll
                    for (int is = 0; is < 8; ++is)
                        __builtin_amdgcn_global_load_lds(
                            (const __attribute__((address_space(1))) void*)(src + (size_t)is * 8 * T_),
                            (__attribute__((address_space(3))) void*)(dst0 + is * 1024), 16, 0, 0);
                }
            }
            if (tid < 128) {
                int tI = tid >> 6, jl = tid & 63;
                int pf = tI ? pfB : pfA;
                if (pf) {
                    int jt = tI ? jtB : jtA;
                    sBias[tI * 64 + jl] = (m[bb * T_ + jt * 64 + jl] != 0.f) ? 0.f : NEGINF_;
                }
            }
        }
        asm volatile("s_waitcnt vmcnt(0)" ::: "memory");
        __syncthreads();

        const int jt = kvpar ? jtB : jtA;
        const int pf = kvpar ? pfB : pfA;
        if (kvpar == 0 || hasB) {
            const int j0 = jt * 64;
            const unsigned short* sKp = kvpar ? sK1 : sK0;
            const unsigned short* sVp = kvpar ? sV1 : sV0;

            // S^T = K Q^T: two 32x32 C-tiles (j 0-31, 32-63)
            f32x16 s0, s1;
#pragma unroll
            for (int rr = 0; rr < 16; ++rr) { s0[rr] = 0.f; s1[rr] = 0.f; }
            __builtin_amdgcn_s_setprio(1);
#pragma unroll
            for (int c = 0; c < 4; ++c) {
                int pc = ((2 * c + hl) ^ swz) * 8;
                short8 ka0 = *(const short8*)(sKp + i31 * 64 + pc);
                short8 ka1 = *(const short8*)(sKp + (32 + i31) * 64 + pc);
                s0 = MFMA32(ka0, bq[c], s0);
                s1 = MFMA32(ka1, bq[c], s1);
            }
            __builtin_amdgcn_s_setprio(0);

            // masks: causal only on diagonal tile; pad bias only if flagged
            if (jt == q) {
#pragma unroll
                for (int qd = 0; qd < 4; ++qd)
#pragma unroll
                    for (int e = 0; e < 4; ++e) {
                        int jl0 = 8 * qd + 4 * hl + e;
                        if (j0 + jl0 > qrow)      s0[qd * 4 + e] = NEGINF_;
                        if (j0 + 32 + jl0 > qrow) s1[qd * 4 + e] = NEGINF_;
                    }
            }
            if (pf) {
#pragma unroll
                for (int qd = 0; qd < 4; ++qd) {
                    f32x4 b0 = *(const f32x4*)(&sBias[kvpar * 64 + 8 * qd + 4 * hl]);
                    f32x4 b1 = *(const f32x4*)(&sBias[kvpar * 64 + 32 + 8 * qd + 4 * hl]);
#pragma unroll
                    for (int e = 0; e < 4; ++e) {
                        s0[qd * 4 + e] += b0[e];
                        s1[qd * 4 + e] += b1[e];
                    }
                }
            }

            // online softmax with defer-max (T13): lane owns q-row qrow
            float pm = NEGINF_;
#pragma unroll
            for (int rr = 0; rr < 16; ++rr)
                pm = fmaxf(pm, fmaxf(s0[rr], s1[rr]));
            pm = fmaxf(pm, __shfl_xor(pm, 32, 64));
            if (__all(pm - mrun <= 8.f)) {
                // deferred: no rescale, keep mrun
                float ls = 0.f;
#pragma unroll
                for (int rr = 0; rr < 16; ++rr) {
                    float p0 = __builtin_amdgcn_exp2f(s0[rr] - mrun);
                    float p1 = __builtin_amdgcn_exp2f(s1[rr] - mrun);
                    s0[rr] = p0; s1[rr] = p1;
                    ls += p0 + p1;
                }
                ls += __shfl_xor(ls, 32, 64);
                lrun += ls;
            } else {
                float mnew = fmaxf(mrun, pm);
                float scl = __builtin_amdgcn_exp2f(mrun - mnew);
                mrun = mnew;
                float ls = 0.f;
#pragma unroll
                for (int rr = 0; rr < 16; ++rr) {
                    float p0 = __builtin_amdgcn_exp2f(s0[rr] - mnew);
                    float p1 = __builtin_amdgcn_exp2f(s1[rr] - mnew);
                    s0[rr] = p0; s1[rr] = p1;
                    ls += p0 + p1;
                }
                ls += __shfl_xor(ls, 32, 64);
                lrun = lrun * scl + ls;
#pragma unroll
                for (int rr = 0; rr < 16; ++rr) { oacc0[rr] *= scl; oacc1[rr] *= scl; }
            }

            // P repack to B-frags in registers: cvt_pk pairs + permlane32_swap
            unsigned int pw0[8], pw1[8];
#pragma unroll
            for (int k2 = 0; k2 < 8; ++k2) {
                unsigned int wa, wb;
                asm("v_cvt_pk_bf16_f32 %0, %1, %2" : "=v"(wa) : "v"(s0[2 * k2]), "v"(s0[2 * k2 + 1]));
                asm("v_cvt_pk_bf16_f32 %0, %1, %2" : "=v"(wb) : "v"(s1[2 * k2]), "v"(s1[2 * k2 + 1]));
                pw0[k2] = wa; pw1[k2] = wb;
            }
            asm("v_permlane32_swap_b32 %0, %1" : "+v"(pw0[0]), "+v"(pw0[2]));
            asm("v_permlane32_swap_b32 %0, %1" : "+v"(pw0[1]), "+v"(pw0[3]));
            asm("v_permlane32_swap_b32 %0, %1" : "+v"(pw0[4]), "+v"(pw0[6]));
            asm("v_permlane32_swap_b32 %0, %1" : "+v"(pw0[5]), "+v"(pw0[7]));
            asm("v_permlane32_swap_b32 %0, %1" : "+v"(pw1[0]), "+v"(pw1[2]));
            asm("v_permlane32_swap_b32 %0, %1" : "+v"(pw1[1]), "+v"(pw1[3]));
            asm("v_permlane32_swap_b32 %0, %1" : "+v"(pw1[4]), "+v"(pw1[6]));
            asm("v_permlane32_swap_b32 %0, %1" : "+v"(pw1[5]), "+v"(pw1[7]));
            union PU { unsigned int u[4]; short8 s8; };
            PU pb[4];
            pb[0].u[0] = pw0[0]; pb[0].u[1] = pw0[1]; pb[0].u[2] = pw0[2]; pb[0].u[3] = pw0[3];
            pb[1].u[0] = pw0[4]; pb[1].u[1] = pw0[5]; pb[1].u[2] = pw0[6]; pb[1].u[3] = pw0[7];
            pb[2].u[0] = pw1[0]; pb[2].u[1] = pw1[1]; pb[2].u[2] = pw1[2]; pb[2].u[3] = pw1[3];
            pb[3].u[0] = pw1[4]; pb[3].u[1] = pw1[5]; pb[3].u[2] = pw1[6]; pb[3].u[3] = pw1[7];

            // PV: O^T(d x i) += V^T-frags x P-frags
            __builtin_amdgcn_s_setprio(1);
#pragma unroll
            for (int c = 0; c < 4; ++c) {
                int pc = ((2 * c + hl) ^ swz) * 8;
                short8 va0 = *(const short8*)(sVp + i31 * 64 + pc);
                short8 va1 = *(const short8*)(sVp + (32 + i31) * 64 + pc);
                oacc0 = MFMA32(va0, pb[c].s8, oacc0);
                oacc1 = MFMA32(va1, pb[c].s8, oacc1);
            }
            __builtin_amdgcn_s_setprio(0);
        }
        __syncthreads();
    }

    // merge odd-half into even-half via LDS (aliased region), then epilogue
    if (kvpar == 1) {
#pragma unroll
        for (int rr = 0; rr < 16; ++rr) {
            sMrgO[(rb * 64 + l) * 33 + rr]      = oacc0[rr];
            sMrgO[(rb * 64 + l) * 33 + 16 + rr] = oacc1[rr];
        }
        sMrgS[(rb * 64 + l) * 2 + 0] = mrun;
        sMrgS[(rb * 64 + l) * 2 + 1] = lrun;
    }
    __syncthreads();
    if (kvpar == 0) {
        float mB = sMrgS[(rb * 64 + l) * 2 + 0], lB = sMrgS[(rb * 64 + l) * 2 + 1];
        float ms = fmaxf(mrun, mB);
        float sA2 = __builtin_amdgcn_exp2f(mrun - ms);
        float sB2 = __builtin_amdgcn_exp2f(mB - ms);
        float lt = lrun * sA2 + lB * sB2;
        float rinv = (lt > 0.f) ? 1.0f / lt : 0.f;
#pragma unroll
        for (int td = 0; td < 2; ++td)
#pragma unroll
            for (int qd = 0; qd < 4; ++qd) {
                ushort4_t o4;
#pragma unroll
                for (int e = 0; e < 4; ++e) {
                    float mine = td ? oacc1[qd * 4 + e] : oacc0[qd * 4 + e];
                    float ov = (mine * sA2 + sMrgO[(rb * 64 + l) * 33 + td * 16 + qd * 4 + e] * sB2) * rinv;
                    o4[e] = f2bf(ov);
                }
                *(ushort4_t*)(o_bf + (size_t)(bb * T_ + qrow) * D_
                              + h * 64 + 32 * td + 8 * qd + 4 * hl) = o4;
            }
    }
}

// ---------------------------------------------------------------------------
extern "C" void kernel_launch(void* const* d_in, const int* in_sizes, int n_in,
                              void* d_out, int out_size, void* d_ws, size_t ws_size,
                              hipStream_t stream)
{
    const float* x     = (const float*)d_in[0];
    const float* m     = (const float*)d_in[1];
    const float* w_qkv = (const float*)d_in[2];
    const float* w_out = (const float*)d_in[3];
    const float* b_out = (const float*)d_in[4];
    float* out = (float*)d_out;

    char* ws = (char*)d_ws;
    unsigned short* x_bf   = (unsigned short*)(ws);                 // 8 MB
    unsigned short* wqkvT  = (unsigned short*)(ws + 8388608);       // 1.5 MB
    unsigned short* woutT  = (unsigned short*)(ws + 9961472);       // 0.5 MB
    unsigned short* qkv_bf = (unsigned short*)(ws + 10485760);      // 24 MB
    unsigned short* o_bf   = (unsigned short*)(ws + 35651584);      // 8 MB
    // d_out (16 MB) dead until gemm_out: vT in [0,8MB), padflags after it
    unsigned short* vT     = (unsigned short*)d_out;                // [32][64][2048] bf16
    int* padflags          = (int*)((char*)d_out + 8388608);        // 128 ints

    hipLaunchKernelGGL(prep_kernel, dim3(6145), dim3(256), 0, stream,
                       x, w_qkv, w_out, m, x_bf, wqkvT, woutT, padflags);
    hipLaunchKernelGGL(gemm_qkv_kernel, dim3(12, 64), dim3(256), 0, stream,
                       x_bf, wqkvT, qkv_bf, vT);
    hipLaunchKernelGGL(attn_kernel, dim3(32, 32), dim3(256), 0, stream,
                       qkv_bf, vT, m, padflags, o_bf);
    hipLaunchKernelGGL(gemm_out_kernel, dim3(4, 64), dim3(256), 0, stream,
                       o_bf, woutT, b_out, m, out);
}